// Round 14
// baseline (279.713 us; speedup 1.0000x reference)
//
#include <hip/hip_runtime.h>
#include <hip/hip_bf16.h>
#include <math.h>

#define N_NODES 50000
#define N_EDGES 1600000
#define TE 64
#define LOG2E 1.44269504088896340736f
#define NBK 196            // dst buckets: bucket = dst >> 8 (256 nodes each)
#define BIN_CHUNK 2048
#define BIN_GRID ((N_EDGES + BIN_CHUNK - 1) / BIN_CHUNK)   // 782

typedef int vint2 __attribute__((ext_vector_type(2)));

// ---------------- node transform ----------------
// h = concat(x, cos(t*omega+phase)) @ W ; also s_src[n,h], s_dst[n,h] (pre-scaled
// by log2e). Register-tiled GEMM: block = 64 nodes x 64 cols, 256 thr = 16x16,
// thread tile 4 nodes x 4 cols.
template<int IN_DIM>
__global__ __launch_bounds__(256) void transform_kernel(
    const float* __restrict__ xin, const float* __restrict__ tim,
    const float* __restrict__ omega, const float* __restrict__ phase,
    const float* __restrict__ W, const float* __restrict__ asrc,
    const float* __restrict__ adst,
    float* __restrict__ hfeat, float* __restrict__ s_src, float* __restrict__ s_dst)
{
    constexpr int K = IN_DIM + TE;
    constexpr int KC = 32;             // k-chunk
    constexpr int NCH = K / KC;
    constexpr int BN = 64;             // nodes per block
    __shared__ float aS[KC][68];       // transposed a-chunk (padded row: 272B)
    __shared__ float wS[KC][64];
    __shared__ float tS[BN];

    const int tid = threadIdx.x;
    const int base = blockIdx.x * BN;

    if (tid < BN) {
        int n = base + tid;
        tS[tid] = (n < N_NODES) ? tim[n] : 0.f;
    }

    const int ty = tid >> 4;           // node quad: nodes ty*4 .. ty*4+3
    const int tx = tid & 15;           // col slot: cols tx*4 .. tx*4+3

    float acc[4][4] = {};

    for (int ch = 0; ch < NCH; ++ch) {
        const int kg0 = ch * KC;
        __syncthreads();               // previous chunk fully consumed

        // stage W chunk: 32x64 floats = 512 float4, 2 per thread (coalesced)
        #pragma unroll
        for (int j = 0; j < 2; ++j) {
            int idx = tid + j * 256;                    // float4 index
            int kk = idx >> 4, c4 = idx & 15;
            *(float4*)&wS[kk][c4 * 4] =
                ((const float4*)(W + (size_t)(kg0 + kk) * 64))[c4];
        }

        // stage a chunk (transposed)
        if (kg0 < IN_DIM) {
            #pragma unroll
            for (int j = 0; j < 2; ++j) {
                int idx = tid + j * 256;
                int nl = idx >> 3, kk = (idx & 7) * 4;
                int n = base + nl;
                float4 v = (n < N_NODES)
                    ? ((const float4*)(xin + (size_t)n * IN_DIM + kg0))[idx & 7]
                    : make_float4(0.f, 0.f, 0.f, 0.f);
                aS[kk + 0][nl] = v.x;
                aS[kk + 1][nl] = v.y;
                aS[kk + 2][nl] = v.z;
                aS[kk + 3][nl] = v.w;
            }
        } else {
            #pragma unroll
            for (int j = 0; j < 8; ++j) {
                int idx = tid + j * 256;
                int kk = idx >> 6, nl = idx & 63;
                int kg = kg0 + kk - IN_DIM;
                aS[kk][nl] = cosf(tS[nl] * omega[kg] + phase[kg]);
            }
        }
        __syncthreads();

        #pragma unroll
        for (int k = 0; k < KC; ++k) {
            const float4 av = *(const float4*)&aS[k][ty * 4];
            const float4 wv = *(const float4*)&wS[k][tx * 4];
            acc[0][0] = fmaf(av.x, wv.x, acc[0][0]);
            acc[0][1] = fmaf(av.x, wv.y, acc[0][1]);
            acc[0][2] = fmaf(av.x, wv.z, acc[0][2]);
            acc[0][3] = fmaf(av.x, wv.w, acc[0][3]);
            acc[1][0] = fmaf(av.y, wv.x, acc[1][0]);
            acc[1][1] = fmaf(av.y, wv.y, acc[1][1]);
            acc[1][2] = fmaf(av.y, wv.z, acc[1][2]);
            acc[1][3] = fmaf(av.y, wv.w, acc[1][3]);
            acc[2][0] = fmaf(av.z, wv.x, acc[2][0]);
            acc[2][1] = fmaf(av.z, wv.y, acc[2][1]);
            acc[2][2] = fmaf(av.z, wv.z, acc[2][2]);
            acc[2][3] = fmaf(av.z, wv.w, acc[2][3]);
            acc[3][0] = fmaf(av.w, wv.x, acc[3][0]);
            acc[3][1] = fmaf(av.w, wv.y, acc[3][1]);
            acc[3][2] = fmaf(av.w, wv.z, acc[3][2]);
            acc[3][3] = fmaf(av.w, wv.w, acc[3][3]);
        }
    }

    // epilogue: hfeat stores + per-head scores
    const float4 as = ((const float4*)asrc)[tx];
    const float4 ad = ((const float4*)adst)[tx];
    #pragma unroll
    for (int j = 0; j < 4; ++j) {
        const int n = base + ty * 4 + j;
        if (n < N_NODES) {
            *(float4*)(hfeat + (size_t)n * 64 + tx * 4) =
                make_float4(acc[j][0], acc[j][1], acc[j][2], acc[j][3]);
        }
        float vs = acc[j][0] * as.x + acc[j][1] * as.y
                 + acc[j][2] * as.z + acc[j][3] * as.w;
        float vd = acc[j][0] * ad.x + acc[j][1] * ad.y
                 + acc[j][2] * ad.z + acc[j][3] * ad.w;
        vs += __shfl_xor(vs, 1, 64); vs += __shfl_xor(vs, 2, 64);
        vd += __shfl_xor(vd, 1, 64); vd += __shfl_xor(vd, 2, 64);
        if ((tx & 3) == 0 && n < N_NODES) {
            s_src[n * 4 + (tx >> 2)] = vs * LOG2E;   // exp2 domain
            s_dst[n * 4 + (tx >> 2)] = vd * LOG2E;
        }
    }
}

// ---------------- CSR build: two-level bucket sort ----------------
// Bucket = dst>>8 (196 buckets x 256 nodes). All random writes are confined
// to windows owned by a SINGLE block (single CU / single L2) -> structural
// write merging, no dependence on block->XCD mapping.

// count bucket sizes (LDS hist, 196 global atomics per block)
__global__ __launch_bounds__(256) void bhist_kernel(
    const int* __restrict__ dst, int* __restrict__ bcnt)
{
    __shared__ int c[NBK];
    for (int t = threadIdx.x; t < NBK; t += 256) c[t] = 0;
    __syncthreads();
    const int base = blockIdx.x * BIN_CHUNK;
    const int end = (base + BIN_CHUNK < N_EDGES) ? base + BIN_CHUNK : N_EDGES;
    for (int e = base + threadIdx.x; e < end; e += 256)
        atomicAdd(&c[dst[e] >> 8], 1);
    __syncthreads();
    for (int t = threadIdx.x; t < NBK; t += 256)
        if (c[t]) atomicAdd(bcnt + t, c[t]);
}

// exclusive scan of bucket counts -> bstart[0..NBK] ; init tails
__global__ __launch_bounds__(256) void bscan_kernel(
    const int* __restrict__ bcnt, int* __restrict__ bstart, int* __restrict__ tail)
{
    __shared__ int s[256];
    const int t = threadIdx.x;
    int v = (t < NBK) ? bcnt[t] : 0;
    s[t] = v;
    __syncthreads();
    #pragma unroll
    for (int off = 1; off < 256; off <<= 1) {
        int u = (t >= off) ? s[t - off] : 0;
        __syncthreads();
        s[t] += u;
        __syncthreads();
    }
    int excl = s[t] - v;
    if (t < NBK) { bstart[t] = excl; tail[t] = excl; }
    if (t == NBK - 1) bstart[NBK] = s[t];
}

// bin edges into bucket regions. Per 2048-edge chunk: LDS-hist ranks, ONE
// global tail atomic per bucket, then writes to 196 contiguous run tails
// (~12KB active window -> L2-merged).
__global__ __launch_bounds__(256) void bin_kernel(
    const int* __restrict__ dst, const int* __restrict__ src,
    const float* __restrict__ ew,
    int* __restrict__ tail, int* __restrict__ rdst, int2* __restrict__ rpair)
{
    __shared__ int cnt[NBK];
    __shared__ int gbase[NBK];
    const int base = blockIdx.x * BIN_CHUNK;
    for (int t = threadIdx.x; t < NBK; t += 256) cnt[t] = 0;
    __syncthreads();

    int d[8], sv[8], rk[8];
    float w[8];
    #pragma unroll
    for (int k = 0; k < 8; ++k) {
        const int e = base + k * 256 + threadIdx.x;
        if (e < N_EDGES) {
            d[k] = dst[e]; sv[k] = src[e]; w[k] = ew[e];
            rk[k] = atomicAdd(&cnt[d[k] >> 8], 1);
        }
    }
    __syncthreads();
    for (int t = threadIdx.x; t < NBK; t += 256)
        gbase[t] = cnt[t] ? atomicAdd(tail + t, cnt[t]) : 0;
    __syncthreads();
    #pragma unroll
    for (int k = 0; k < 8; ++k) {
        const int e = base + k * 256 + threadIdx.x;
        if (e < N_EDGES) {
            const int pos = gbase[d[k] >> 8] + rk[k];
            rdst[pos] = d[k];
            rpair[pos] = make_int2(sv[k], __float_as_int(w[k]));
        }
    }
}

// one block per bucket: build deg/rowptr locally (LDS hist+scan) then place
// epair via LDS cursors. rpair is read ONCE -> non-temporal (protects the
// epair write window in this CU's L2); rdst is read twice -> temporal.
__global__ __launch_bounds__(256) void place_kernel(
    const int* __restrict__ bstart, const int* __restrict__ rdst,
    const int2* __restrict__ rpair,
    int* __restrict__ deg, int* __restrict__ rowptr, int2* __restrict__ epair)
{
    __shared__ int ldeg[256];
    __shared__ int ls[256];
    __shared__ int lcur[256];
    const int t = threadIdx.x;
    const int b = blockIdx.x;
    const int lo = bstart[b], hi = bstart[b + 1];
    const int nbase = b << 8;

    ldeg[t] = 0;
    __syncthreads();
    for (int i = lo + t; i < hi; i += 256)
        atomicAdd(&ldeg[rdst[i] & 255], 1);
    __syncthreads();

    const int v = ldeg[t];
    ls[t] = v;
    __syncthreads();
    #pragma unroll
    for (int off = 1; off < 256; off <<= 1) {
        int u = (t >= off) ? ls[t - off] : 0;
        __syncthreads();
        ls[t] += u;
        __syncthreads();
    }
    const int excl = ls[t] - v + lo;
    const int n = nbase + t;
    if (n < N_NODES) { rowptr[n] = excl; deg[n] = v; }
    lcur[t] = excl;
    __syncthreads();

    const vint2* rpv = (const vint2*)rpair;
    for (int i = lo + t; i < hi; i += 256) {
        const int d = rdst[i];
        vint2 rp = __builtin_nontemporal_load(rpv + i);
        const int pos = atomicAdd(&lcur[d & 255], 1);
        epair[pos] = make_int2(rp.x, rp.y);
    }
}

// ---------------- fused per-dst aggregation ----------------
// one wave per node; 16 subgroups x 4 lanes, 16 edges in flight per iteration
// (+depth-1 prefetch -> ~32 outstanding). Each lane owns ONE head: features
// [sl*16, sl*16+16) as 4x float4. Concurrency probe vs round-13's 8x8: if
// latency/Little's-law-bound this ~2x outstanding-bytes should cut dur; if
// the L2-miss path is saturated it will be neutral.
// no max-subtraction (scores O(1), softmax shift-invariant); exp2 domain.
template<int FINAL>
__global__ __launch_bounds__(256) void aggregate_kernel(
    const int* __restrict__ rowptr, const int* __restrict__ deg,
    const int2* __restrict__ epair,
    const float* __restrict__ s_src, const float* __restrict__ s_dst,
    const float* __restrict__ hfeat,
    const float* __restrict__ whead, const float* __restrict__ bhead,
    float* __restrict__ outp)
{
    const int n = blockIdx.x * 4 + (threadIdx.x >> 6);
    if (n >= N_NODES) return;
    const int lane = threadIdx.x & 63;
    const int g = lane >> 2;          // subgroup (edge slot 0..15)
    const int sl = lane & 3;          // head index; features sl*16..sl*16+15
    const float sdst = s_dst[n * 4 + sl];
    const int beg = rowptr[n];
    const int cnt = deg[n];
    const vint2* epv = (const vint2*)epair + beg;
    const vint2 zz = {0, 0};

    float den = 0.f;
    float4 a0 = make_float4(0.f, 0.f, 0.f, 0.f);
    float4 a1 = make_float4(0.f, 0.f, 0.f, 0.f);
    float4 a2 = make_float4(0.f, 0.f, 0.f, 0.f);
    float4 a3 = make_float4(0.f, 0.f, 0.f, 0.f);

    int i = g;
    vint2 ep = (i < cnt) ? __builtin_nontemporal_load(epv + i) : zz;
    float ss = s_src[(size_t)ep.x * 4 + sl];
    const float4* hp = (const float4*)(hfeat + (size_t)ep.x * 64 + sl * 16);
    float4 h0 = hp[0], h1 = hp[1], h2 = hp[2], h3 = hp[3];

    while (i < cnt) {
        const int inext = i + 16;
        // prefetch step i+16 (out-of-range -> harmless row 0 reads)
        vint2 epn = (inext < cnt) ? __builtin_nontemporal_load(epv + inext) : zz;
        float ssn = s_src[(size_t)epn.x * 4 + sl];
        const float4* hpn = (const float4*)(hfeat + (size_t)epn.x * 64 + sl * 16);
        float4 h0n = hpn[0], h1n = hpn[1], h2n = hpn[2], h3n = hpn[3];

        const float w = __int_as_float(ep.y);
        float sc = ss + sdst;
        sc = fmaxf(sc, 0.2f * sc);                       // leaky relu (log2 domain)
        const float p = __builtin_amdgcn_exp2f(sc) * w;
        den += p;
        a0.x = fmaf(p, h0.x, a0.x); a0.y = fmaf(p, h0.y, a0.y);
        a0.z = fmaf(p, h0.z, a0.z); a0.w = fmaf(p, h0.w, a0.w);
        a1.x = fmaf(p, h1.x, a1.x); a1.y = fmaf(p, h1.y, a1.y);
        a1.z = fmaf(p, h1.z, a1.z); a1.w = fmaf(p, h1.w, a1.w);
        a2.x = fmaf(p, h2.x, a2.x); a2.y = fmaf(p, h2.y, a2.y);
        a2.z = fmaf(p, h2.z, a2.z); a2.w = fmaf(p, h2.w, a2.w);
        a3.x = fmaf(p, h3.x, a3.x); a3.y = fmaf(p, h3.y, a3.y);
        a3.z = fmaf(p, h3.z, a3.z); a3.w = fmaf(p, h3.w, a3.w);

        ep = epn; ss = ssn;
        h0 = h0n; h1 = h1n; h2 = h2n; h3 = h3n;
        i = inext;
    }

    // merge 16 subgroups (lane bits 2..5); lanes with equal sl share features
    #pragma unroll
    for (int off = 4; off <= 32; off <<= 1) {
        den  += __shfl_xor(den, off, 64);
        a0.x += __shfl_xor(a0.x, off, 64); a0.y += __shfl_xor(a0.y, off, 64);
        a0.z += __shfl_xor(a0.z, off, 64); a0.w += __shfl_xor(a0.w, off, 64);
        a1.x += __shfl_xor(a1.x, off, 64); a1.y += __shfl_xor(a1.y, off, 64);
        a1.z += __shfl_xor(a1.z, off, 64); a1.w += __shfl_xor(a1.w, off, 64);
        a2.x += __shfl_xor(a2.x, off, 64); a2.y += __shfl_xor(a2.y, off, 64);
        a2.z += __shfl_xor(a2.z, off, 64); a2.w += __shfl_xor(a2.w, off, 64);
        a3.x += __shfl_xor(a3.x, off, 64); a3.y += __shfl_xor(a3.y, off, 64);
        a3.z += __shfl_xor(a3.z, off, 64); a3.w += __shfl_xor(a3.w, off, 64);
    }

    const float inv = 1.f / (den + 1e-16f);
    if (!FINAL) {
        if (g == 0) {
            float4 o[4] = {a0, a1, a2, a3};
            float4* op = (float4*)(outp + (size_t)n * 64 + sl * 16);
            #pragma unroll
            for (int j = 0; j < 4; ++j) {
                float4 v;
                v.x = o[j].x * inv; v.x = v.x > 0.f ? v.x : expm1f(v.x);
                v.y = o[j].y * inv; v.y = v.y > 0.f ? v.y : expm1f(v.y);
                v.z = o[j].z * inv; v.z = v.z > 0.f ? v.z : expm1f(v.z);
                v.w = o[j].w * inv; v.w = v.w > 0.f ? v.w : expm1f(v.w);
                op[j] = v;
            }
        }
    } else {
        const float4* wp = (const float4*)(whead + sl * 16);
        const float4 w0 = wp[0], w1 = wp[1], w2 = wp[2], w3 = wp[3];
        float v = (a0.x * w0.x + a0.y * w0.y + a0.z * w0.z + a0.w * w0.w
                 + a1.x * w1.x + a1.y * w1.y + a1.z * w1.z + a1.w * w1.w
                 + a2.x * w2.x + a2.y * w2.y + a2.z * w2.z + a2.w * w2.w
                 + a3.x * w3.x + a3.y * w3.y + a3.z * w3.z + a3.w * w3.w) * inv;
        v += __shfl_xor(v, 1, 64);
        v += __shfl_xor(v, 2, 64);
        if (lane == 0) outp[n] = v + bhead[0];
    }
}

extern "C" void kernel_launch(void* const* d_in, const int* in_sizes, int n_in,
                              void* d_out, int out_size, void* d_ws, size_t ws_size,
                              hipStream_t stream) {
    const float* x      = (const float*)d_in[0];
    const int*   eidx   = (const int*)d_in[1];
    const float* ew     = (const float*)d_in[2];
    const float* tim    = (const float*)d_in[3];
    const float* omega0 = (const float*)d_in[4];
    const float* phase0 = (const float*)d_in[5];
    const float* W0     = (const float*)d_in[6];
    const float* asrc0  = (const float*)d_in[7];
    const float* adst0  = (const float*)d_in[8];
    const float* omega1 = (const float*)d_in[9];
    const float* phase1 = (const float*)d_in[10];
    const float* W1     = (const float*)d_in[11];
    const float* asrc1  = (const float*)d_in[12];
    const float* adst1  = (const float*)d_in[13];
    const float* Whead  = (const float*)d_in[14];
    const float* bhead  = (const float*)d_in[15];
    float* out = (float*)d_out;

    const int* src = eidx;
    const int* dst = eidx + N_EDGES;

    float* ws = (float*)d_ws;
    float* hfeat = ws;                               // N*64 (3.2M words)
    float* x1    = hfeat + (size_t)N_NODES * 64;     // N*64 (3.2M words)
    float* s_src = x1    + (size_t)N_NODES * 64;     // N*4
    float* s_dst = s_src + (size_t)N_NODES * 4;      // N*4
    int2* epair  = (int2*)(s_dst + (size_t)N_NODES * 4);   // E int2
    int* deg     = (int*)(epair + (size_t)N_EDGES);  // N
    int* rowptr  = deg + N_NODES;                    // N
    int* bcnt    = rowptr + N_NODES;                 // NBK
    int* bstart  = bcnt + NBK;                       // NBK+1
    int* tail    = bstart + NBK + 1;                 // NBK
    // record arrays alias dead buffers: consumed by place() before their
    // aliases are written (hfeat by transform<128>, x1 by aggregate<0>)
    int*  rdst  = (int*)hfeat;                       // E ints  (<= N*64)
    int2* rpair = (int2*)x1;                         // E int2  (== N*64 words)

    const int tf_grid  = (N_NODES + 63) / 64;        // 782
    const int agg_grid = (N_NODES + 3) / 4;

    // ---- CSR build (two-level bucket sort; shared by both layers) ----
    hipMemsetAsync(bcnt, 0, NBK * sizeof(int), stream);
    bhist_kernel<<<BIN_GRID, 256, 0, stream>>>(dst, bcnt);
    bscan_kernel<<<1, 256, 0, stream>>>(bcnt, bstart, tail);
    bin_kernel<<<BIN_GRID, 256, 0, stream>>>(dst, src, ew, tail, rdst, rpair);
    place_kernel<<<NBK, 256, 0, stream>>>(bstart, rdst, rpair, deg, rowptr, epair);

    // ---- layer 0 ----
    transform_kernel<128><<<tf_grid, 256, 0, stream>>>(
        x, tim, omega0, phase0, W0, asrc0, adst0, hfeat, s_src, s_dst);
    aggregate_kernel<0><<<agg_grid, 256, 0, stream>>>(
        rowptr, deg, epair, s_src, s_dst, hfeat, Whead, bhead, x1);

    // ---- layer 1 (+ fused linear head) ----
    transform_kernel<64><<<tf_grid, 256, 0, stream>>>(
        x1, tim, omega1, phase1, W1, asrc1, adst1, hfeat, s_src, s_dst);
    aggregate_kernel<1><<<agg_grid, 256, 0, stream>>>(
        rowptr, deg, epair, s_src, s_dst, hfeat, Whead, bhead, out);
}

// Round 15
// 254.082 us; speedup vs baseline: 1.1009x; 1.1009x over previous
//
#include <hip/hip_runtime.h>
#include <hip/hip_bf16.h>
#include <math.h>

#define N_NODES 50000
#define N_EDGES 1600000
#define TE 64
#define LOG2E 1.44269504088896340736f
#define NBK 196            // dst buckets: bucket = dst >> 8 (256 nodes each)
#define BIN_CHUNK 2048
#define BIN_GRID ((N_EDGES + BIN_CHUNK - 1) / BIN_CHUNK)   // 782

typedef int vint2 __attribute__((ext_vector_type(2)));
typedef unsigned int uint;

__device__ __forceinline__ unsigned short f2bf(float f) {
    uint u = __float_as_uint(f);
    return (unsigned short)((u + 0x7fffu + ((u >> 16) & 1u)) >> 16);   // RNE
}
__device__ __forceinline__ float bf_lo(uint u) { return __uint_as_float(u << 16); }
__device__ __forceinline__ float bf_hi(uint u) { return __uint_as_float(u & 0xffff0000u); }

// ---------------- node transform ----------------
// h = concat(x, cos(t*omega+phase)) @ W ; h stored as BF16 (gather table is
// the aggregate's bandwidth floor: bf16 halves the bytes; scores stay fp32).
// Register-tiled GEMM: block = 64 nodes x 64 cols, 256 thr = 16x16, thread
// tile 4 nodes x 4 cols.
template<int IN_DIM>
__global__ __launch_bounds__(256) void transform_kernel(
    const float* __restrict__ xin, const float* __restrict__ tim,
    const float* __restrict__ omega, const float* __restrict__ phase,
    const float* __restrict__ W, const float* __restrict__ asrc,
    const float* __restrict__ adst,
    unsigned short* __restrict__ hfeat16,
    float* __restrict__ s_src, float* __restrict__ s_dst)
{
    constexpr int K = IN_DIM + TE;
    constexpr int KC = 32;             // k-chunk
    constexpr int NCH = K / KC;
    constexpr int BN = 64;             // nodes per block
    __shared__ float aS[KC][68];       // transposed a-chunk (padded row: 272B)
    __shared__ float wS[KC][64];
    __shared__ float tS[BN];

    const int tid = threadIdx.x;
    const int base = blockIdx.x * BN;

    if (tid < BN) {
        int n = base + tid;
        tS[tid] = (n < N_NODES) ? tim[n] : 0.f;
    }

    const int ty = tid >> 4;           // node quad: nodes ty*4 .. ty*4+3
    const int tx = tid & 15;           // col slot: cols tx*4 .. tx*4+3

    float acc[4][4] = {};

    for (int ch = 0; ch < NCH; ++ch) {
        const int kg0 = ch * KC;
        __syncthreads();               // previous chunk fully consumed

        // stage W chunk: 32x64 floats = 512 float4, 2 per thread (coalesced)
        #pragma unroll
        for (int j = 0; j < 2; ++j) {
            int idx = tid + j * 256;                    // float4 index
            int kk = idx >> 4, c4 = idx & 15;
            *(float4*)&wS[kk][c4 * 4] =
                ((const float4*)(W + (size_t)(kg0 + kk) * 64))[c4];
        }

        // stage a chunk (transposed)
        if (kg0 < IN_DIM) {
            #pragma unroll
            for (int j = 0; j < 2; ++j) {
                int idx = tid + j * 256;
                int nl = idx >> 3, kk = (idx & 7) * 4;
                int n = base + nl;
                float4 v = (n < N_NODES)
                    ? ((const float4*)(xin + (size_t)n * IN_DIM + kg0))[idx & 7]
                    : make_float4(0.f, 0.f, 0.f, 0.f);
                aS[kk + 0][nl] = v.x;
                aS[kk + 1][nl] = v.y;
                aS[kk + 2][nl] = v.z;
                aS[kk + 3][nl] = v.w;
            }
        } else {
            #pragma unroll
            for (int j = 0; j < 8; ++j) {
                int idx = tid + j * 256;
                int kk = idx >> 6, nl = idx & 63;
                int kg = kg0 + kk - IN_DIM;
                aS[kk][nl] = cosf(tS[nl] * omega[kg] + phase[kg]);
            }
        }
        __syncthreads();

        #pragma unroll
        for (int k = 0; k < KC; ++k) {
            const float4 av = *(const float4*)&aS[k][ty * 4];
            const float4 wv = *(const float4*)&wS[k][tx * 4];
            acc[0][0] = fmaf(av.x, wv.x, acc[0][0]);
            acc[0][1] = fmaf(av.x, wv.y, acc[0][1]);
            acc[0][2] = fmaf(av.x, wv.z, acc[0][2]);
            acc[0][3] = fmaf(av.x, wv.w, acc[0][3]);
            acc[1][0] = fmaf(av.y, wv.x, acc[1][0]);
            acc[1][1] = fmaf(av.y, wv.y, acc[1][1]);
            acc[1][2] = fmaf(av.y, wv.z, acc[1][2]);
            acc[1][3] = fmaf(av.y, wv.w, acc[1][3]);
            acc[2][0] = fmaf(av.z, wv.x, acc[2][0]);
            acc[2][1] = fmaf(av.z, wv.y, acc[2][1]);
            acc[2][2] = fmaf(av.z, wv.z, acc[2][2]);
            acc[2][3] = fmaf(av.z, wv.w, acc[2][3]);
            acc[3][0] = fmaf(av.w, wv.x, acc[3][0]);
            acc[3][1] = fmaf(av.w, wv.y, acc[3][1]);
            acc[3][2] = fmaf(av.w, wv.z, acc[3][2]);
            acc[3][3] = fmaf(av.w, wv.w, acc[3][3]);
        }
    }

    // epilogue: hfeat16 stores (bf16) + per-head scores (fp32)
    const float4 as = ((const float4*)asrc)[tx];
    const float4 ad = ((const float4*)adst)[tx];
    #pragma unroll
    for (int j = 0; j < 4; ++j) {
        const int n = base + ty * 4 + j;
        if (n < N_NODES) {
            ushort4 o;
            o.x = f2bf(acc[j][0]); o.y = f2bf(acc[j][1]);
            o.z = f2bf(acc[j][2]); o.w = f2bf(acc[j][3]);
            *(ushort4*)(hfeat16 + (size_t)n * 64 + tx * 4) = o;
        }
        float vs = acc[j][0] * as.x + acc[j][1] * as.y
                 + acc[j][2] * as.z + acc[j][3] * as.w;
        float vd = acc[j][0] * ad.x + acc[j][1] * ad.y
                 + acc[j][2] * ad.z + acc[j][3] * ad.w;
        vs += __shfl_xor(vs, 1, 64); vs += __shfl_xor(vs, 2, 64);
        vd += __shfl_xor(vd, 1, 64); vd += __shfl_xor(vd, 2, 64);
        if ((tx & 3) == 0 && n < N_NODES) {
            s_src[n * 4 + (tx >> 2)] = vs * LOG2E;   // exp2 domain
            s_dst[n * 4 + (tx >> 2)] = vd * LOG2E;
        }
    }
}

// ---------------- CSR build: two-level bucket sort ----------------
// Bucket = dst>>8 (196 buckets x 256 nodes). All random writes are confined
// to windows owned by a SINGLE block (single CU / single L2) -> structural
// write merging, no dependence on block->XCD mapping.

__global__ __launch_bounds__(256) void bhist_kernel(
    const int* __restrict__ dst, int* __restrict__ bcnt)
{
    __shared__ int c[NBK];
    for (int t = threadIdx.x; t < NBK; t += 256) c[t] = 0;
    __syncthreads();
    const int base = blockIdx.x * BIN_CHUNK;
    const int end = (base + BIN_CHUNK < N_EDGES) ? base + BIN_CHUNK : N_EDGES;
    for (int e = base + threadIdx.x; e < end; e += 256)
        atomicAdd(&c[dst[e] >> 8], 1);
    __syncthreads();
    for (int t = threadIdx.x; t < NBK; t += 256)
        if (c[t]) atomicAdd(bcnt + t, c[t]);
}

__global__ __launch_bounds__(256) void bscan_kernel(
    const int* __restrict__ bcnt, int* __restrict__ bstart, int* __restrict__ tail)
{
    __shared__ int s[256];
    const int t = threadIdx.x;
    int v = (t < NBK) ? bcnt[t] : 0;
    s[t] = v;
    __syncthreads();
    #pragma unroll
    for (int off = 1; off < 256; off <<= 1) {
        int u = (t >= off) ? s[t - off] : 0;
        __syncthreads();
        s[t] += u;
        __syncthreads();
    }
    int excl = s[t] - v;
    if (t < NBK) { bstart[t] = excl; tail[t] = excl; }
    if (t == NBK - 1) bstart[NBK] = s[t];
}

__global__ __launch_bounds__(256) void bin_kernel(
    const int* __restrict__ dst, const int* __restrict__ src,
    const float* __restrict__ ew,
    int* __restrict__ tail, int* __restrict__ rdst, int2* __restrict__ rpair)
{
    __shared__ int cnt[NBK];
    __shared__ int gbase[NBK];
    const int base = blockIdx.x * BIN_CHUNK;
    for (int t = threadIdx.x; t < NBK; t += 256) cnt[t] = 0;
    __syncthreads();

    int d[8], sv[8], rk[8];
    float w[8];
    #pragma unroll
    for (int k = 0; k < 8; ++k) {
        const int e = base + k * 256 + threadIdx.x;
        if (e < N_EDGES) {
            d[k] = dst[e]; sv[k] = src[e]; w[k] = ew[e];
            rk[k] = atomicAdd(&cnt[d[k] >> 8], 1);
        }
    }
    __syncthreads();
    for (int t = threadIdx.x; t < NBK; t += 256)
        gbase[t] = cnt[t] ? atomicAdd(tail + t, cnt[t]) : 0;
    __syncthreads();
    #pragma unroll
    for (int k = 0; k < 8; ++k) {
        const int e = base + k * 256 + threadIdx.x;
        if (e < N_EDGES) {
            const int pos = gbase[d[k] >> 8] + rk[k];
            rdst[pos] = d[k];
            rpair[pos] = make_int2(sv[k], __float_as_int(w[k]));
        }
    }
}

__global__ __launch_bounds__(256) void place_kernel(
    const int* __restrict__ bstart, const int* __restrict__ rdst,
    const int2* __restrict__ rpair,
    int* __restrict__ deg, int* __restrict__ rowptr, int2* __restrict__ epair)
{
    __shared__ int ldeg[256];
    __shared__ int ls[256];
    __shared__ int lcur[256];
    const int t = threadIdx.x;
    const int b = blockIdx.x;
    const int lo = bstart[b], hi = bstart[b + 1];
    const int nbase = b << 8;

    ldeg[t] = 0;
    __syncthreads();
    for (int i = lo + t; i < hi; i += 256)
        atomicAdd(&ldeg[rdst[i] & 255], 1);
    __syncthreads();

    const int v = ldeg[t];
    ls[t] = v;
    __syncthreads();
    #pragma unroll
    for (int off = 1; off < 256; off <<= 1) {
        int u = (t >= off) ? ls[t - off] : 0;
        __syncthreads();
        ls[t] += u;
        __syncthreads();
    }
    const int excl = ls[t] - v + lo;
    const int n = nbase + t;
    if (n < N_NODES) { rowptr[n] = excl; deg[n] = v; }
    lcur[t] = excl;
    __syncthreads();

    const vint2* rpv = (const vint2*)rpair;
    for (int i = lo + t; i < hi; i += 256) {
        const int d = rdst[i];
        vint2 rp = __builtin_nontemporal_load(rpv + i);
        const int pos = atomicAdd(&lcur[d & 255], 1);
        epair[pos] = make_int2(rp.x, rp.y);
    }
}

// ---------------- fused per-dst aggregation ----------------
// one wave per node; 8 subgroups x 8 lanes, 8 edges in flight; each lane
// holds 8 bf16 features (ONE uint4 = 16B load, unpacked in-register).
// Round-12 loop shape (best measured); epair read non-temporally.
// no max-subtraction (scores O(1), softmax shift-invariant); exp2 domain.
template<int FINAL>
__global__ __launch_bounds__(256) void aggregate_kernel(
    const int* __restrict__ rowptr, const int* __restrict__ deg,
    const int2* __restrict__ epair,
    const float* __restrict__ s_src, const float* __restrict__ s_dst,
    const unsigned short* __restrict__ hfeat16,
    const float* __restrict__ whead, const float* __restrict__ bhead,
    float* __restrict__ outp)
{
    const int n = blockIdx.x * 4 + (threadIdx.x >> 6);
    if (n >= N_NODES) return;
    const int lane = threadIdx.x & 63;
    const int g = lane >> 3;          // subgroup (edge slot 0..7)
    const int sl = lane & 7;          // feature octet
    const int hh = sl >> 1;           // head of my features
    const float sdst = s_dst[n * 4 + hh];
    const int beg = rowptr[n];
    const int cnt = deg[n];
    const vint2* epv = (const vint2*)epair + beg;
    const vint2 zz = {0, 0};

    float den = 0.f;
    float4 a0 = make_float4(0.f, 0.f, 0.f, 0.f);
    float4 a1 = make_float4(0.f, 0.f, 0.f, 0.f);

    int i = g;
    vint2 ep = (i < cnt) ? __builtin_nontemporal_load(epv + i) : zz;
    while (i < cnt) {
        const int inext = i + 8;
        vint2 epn = (inext < cnt) ? __builtin_nontemporal_load(epv + inext) : zz;
        const int s = ep.x;
        const float w = __int_as_float(ep.y);
        float sc = s_src[(size_t)s * 4 + hh] + sdst;
        sc = fmaxf(sc, 0.2f * sc);                       // leaky relu (log2 domain)
        const float p = __builtin_amdgcn_exp2f(sc) * w;
        const uint4 hv = *(const uint4*)(hfeat16 + (size_t)s * 64 + sl * 8);
        den += p;
        a0.x = fmaf(p, bf_lo(hv.x), a0.x); a0.y = fmaf(p, bf_hi(hv.x), a0.y);
        a0.z = fmaf(p, bf_lo(hv.y), a0.z); a0.w = fmaf(p, bf_hi(hv.y), a0.w);
        a1.x = fmaf(p, bf_lo(hv.z), a1.x); a1.y = fmaf(p, bf_hi(hv.z), a1.y);
        a1.z = fmaf(p, bf_lo(hv.w), a1.z); a1.w = fmaf(p, bf_hi(hv.w), a1.w);
        ep = epn; i = inext;
    }

    // merge 8 subgroups (lane bits 3,4,5)
    #pragma unroll
    for (int off = 8; off <= 32; off <<= 1) {
        den  += __shfl_xor(den, off, 64);
        a0.x += __shfl_xor(a0.x, off, 64); a0.y += __shfl_xor(a0.y, off, 64);
        a0.z += __shfl_xor(a0.z, off, 64); a0.w += __shfl_xor(a0.w, off, 64);
        a1.x += __shfl_xor(a1.x, off, 64); a1.y += __shfl_xor(a1.y, off, 64);
        a1.z += __shfl_xor(a1.z, off, 64); a1.w += __shfl_xor(a1.w, off, 64);
    }

    const float inv = 1.f / (den + 1e-16f);
    if (!FINAL) {
        if (g == 0) {
            float4 v0, v1;
            v0.x = a0.x * inv; v0.x = v0.x > 0.f ? v0.x : expm1f(v0.x);
            v0.y = a0.y * inv; v0.y = v0.y > 0.f ? v0.y : expm1f(v0.y);
            v0.z = a0.z * inv; v0.z = v0.z > 0.f ? v0.z : expm1f(v0.z);
            v0.w = a0.w * inv; v0.w = v0.w > 0.f ? v0.w : expm1f(v0.w);
            v1.x = a1.x * inv; v1.x = v1.x > 0.f ? v1.x : expm1f(v1.x);
            v1.y = a1.y * inv; v1.y = v1.y > 0.f ? v1.y : expm1f(v1.y);
            v1.z = a1.z * inv; v1.z = v1.z > 0.f ? v1.z : expm1f(v1.z);
            v1.w = a1.w * inv; v1.w = v1.w > 0.f ? v1.w : expm1f(v1.w);
            float4* op = (float4*)(outp + (size_t)n * 64 + sl * 8);
            op[0] = v0; op[1] = v1;
        }
    } else {
        const float4* wp = (const float4*)(whead + sl * 8);
        const float4 w0 = wp[0], w1 = wp[1];
        float v = (a0.x * w0.x + a0.y * w0.y + a0.z * w0.z + a0.w * w0.w
                 + a1.x * w1.x + a1.y * w1.y + a1.z * w1.z + a1.w * w1.w) * inv;
        #pragma unroll
        for (int off = 1; off <= 4; off <<= 1) v += __shfl_xor(v, off, 64);
        if (lane == 0) outp[n] = v + bhead[0];
    }
}

extern "C" void kernel_launch(void* const* d_in, const int* in_sizes, int n_in,
                              void* d_out, int out_size, void* d_ws, size_t ws_size,
                              hipStream_t stream) {
    const float* x      = (const float*)d_in[0];
    const int*   eidx   = (const int*)d_in[1];
    const float* ew     = (const float*)d_in[2];
    const float* tim    = (const float*)d_in[3];
    const float* omega0 = (const float*)d_in[4];
    const float* phase0 = (const float*)d_in[5];
    const float* W0     = (const float*)d_in[6];
    const float* asrc0  = (const float*)d_in[7];
    const float* adst0  = (const float*)d_in[8];
    const float* omega1 = (const float*)d_in[9];
    const float* phase1 = (const float*)d_in[10];
    const float* W1     = (const float*)d_in[11];
    const float* asrc1  = (const float*)d_in[12];
    const float* adst1  = (const float*)d_in[13];
    const float* Whead  = (const float*)d_in[14];
    const float* bhead  = (const float*)d_in[15];
    float* out = (float*)d_out;

    const int* src = eidx;
    const int* dst = eidx + N_EDGES;

    float* ws = (float*)d_ws;
    unsigned short* hfeat16 = (unsigned short*)ws;   // N*64 ushorts (6.4MB)
    float* x1    = (float*)(hfeat16 + (size_t)N_NODES * 64);  // N*64 floats
    float* s_src = x1    + (size_t)N_NODES * 64;     // N*4
    float* s_dst = s_src + (size_t)N_NODES * 4;      // N*4
    int2* epair  = (int2*)(s_dst + (size_t)N_NODES * 4);   // E int2
    int* deg     = (int*)(epair + (size_t)N_EDGES);  // N
    int* rowptr  = deg + N_NODES;                    // N
    int* bcnt    = rowptr + N_NODES;                 // NBK
    int* bstart  = bcnt + NBK;                       // NBK+1
    int* tail    = bstart + NBK + 1;                 // NBK
    // record arrays alias dead buffers: consumed by place() before their
    // aliases are written (hfeat16 by transform<128>, x1 by aggregate<0>).
    // E*4B == N*64*2B exactly (6.4MB); E*8B == N*64*4B (12.8MB).
    int*  rdst  = (int*)hfeat16;                     // E ints
    int2* rpair = (int2*)x1;                         // E int2

    const int tf_grid  = (N_NODES + 63) / 64;        // 782
    const int agg_grid = (N_NODES + 3) / 4;

    // ---- CSR build (two-level bucket sort; shared by both layers) ----
    hipMemsetAsync(bcnt, 0, NBK * sizeof(int), stream);
    bhist_kernel<<<BIN_GRID, 256, 0, stream>>>(dst, bcnt);
    bscan_kernel<<<1, 256, 0, stream>>>(bcnt, bstart, tail);
    bin_kernel<<<BIN_GRID, 256, 0, stream>>>(dst, src, ew, tail, rdst, rpair);
    place_kernel<<<NBK, 256, 0, stream>>>(bstart, rdst, rpair, deg, rowptr, epair);

    // ---- layer 0 ----
    transform_kernel<128><<<tf_grid, 256, 0, stream>>>(
        x, tim, omega0, phase0, W0, asrc0, adst0, hfeat16, s_src, s_dst);
    aggregate_kernel<0><<<agg_grid, 256, 0, stream>>>(
        rowptr, deg, epair, s_src, s_dst, hfeat16, Whead, bhead, x1);

    // ---- layer 1 (+ fused linear head) ----
    transform_kernel<64><<<tf_grid, 256, 0, stream>>>(
        x1, tim, omega1, phase1, W1, asrc1, adst1, hfeat16, s_src, s_dst);
    aggregate_kernel<1><<<agg_grid, 256, 0, stream>>>(
        rowptr, deg, epair, s_src, s_dst, hfeat16, Whead, bhead, out);
}

// Round 16
// 244.012 us; speedup vs baseline: 1.1463x; 1.0413x over previous
//
#include <hip/hip_runtime.h>
#include <hip/hip_bf16.h>
#include <math.h>

#define N_NODES 50000
#define N_EDGES 1600000
#define TE 64
#define LOG2E 1.44269504088896340736f
#define NBK 196            // dst buckets: bucket = dst >> 8 (256 nodes each)
#define BIN_CHUNK 4096
#define BIN_GRID ((N_EDGES + BIN_CHUNK - 1) / BIN_CHUNK)   // 391

typedef int vint2 __attribute__((ext_vector_type(2)));
typedef int vint4 __attribute__((ext_vector_type(4)));
typedef float vfloat4 __attribute__((ext_vector_type(4)));
typedef unsigned int uint;

__device__ __forceinline__ unsigned short f2bf(float f) {
    uint u = __float_as_uint(f);
    return (unsigned short)((u + 0x7fffu + ((u >> 16) & 1u)) >> 16);   // RNE
}
__device__ __forceinline__ float bf_lo(uint u) { return __uint_as_float(u << 16); }
__device__ __forceinline__ float bf_hi(uint u) { return __uint_as_float(u & 0xffff0000u); }

// ---------------- node transform ----------------
// h = concat(x, cos(t*omega+phase)) @ W ; h stored as BF16 (gather table is
// the aggregate's bandwidth floor: bf16 halves the bytes; scores stay fp32).
// Register-tiled GEMM: block = 64 nodes x 64 cols, 256 thr = 16x16, thread
// tile 4 nodes x 4 cols.
template<int IN_DIM>
__global__ __launch_bounds__(256) void transform_kernel(
    const float* __restrict__ xin, const float* __restrict__ tim,
    const float* __restrict__ omega, const float* __restrict__ phase,
    const float* __restrict__ W, const float* __restrict__ asrc,
    const float* __restrict__ adst,
    unsigned short* __restrict__ hfeat16,
    float* __restrict__ s_src, float* __restrict__ s_dst)
{
    constexpr int K = IN_DIM + TE;
    constexpr int KC = 32;             // k-chunk
    constexpr int NCH = K / KC;
    constexpr int BN = 64;             // nodes per block
    __shared__ float aS[KC][68];       // transposed a-chunk (padded row: 272B)
    __shared__ float wS[KC][64];
    __shared__ float tS[BN];

    const int tid = threadIdx.x;
    const int base = blockIdx.x * BN;

    if (tid < BN) {
        int n = base + tid;
        tS[tid] = (n < N_NODES) ? tim[n] : 0.f;
    }

    const int ty = tid >> 4;           // node quad: nodes ty*4 .. ty*4+3
    const int tx = tid & 15;           // col slot: cols tx*4 .. tx*4+3

    float acc[4][4] = {};

    for (int ch = 0; ch < NCH; ++ch) {
        const int kg0 = ch * KC;
        __syncthreads();               // previous chunk fully consumed

        // stage W chunk: 32x64 floats = 512 float4, 2 per thread (coalesced)
        #pragma unroll
        for (int j = 0; j < 2; ++j) {
            int idx = tid + j * 256;                    // float4 index
            int kk = idx >> 4, c4 = idx & 15;
            *(float4*)&wS[kk][c4 * 4] =
                ((const float4*)(W + (size_t)(kg0 + kk) * 64))[c4];
        }

        // stage a chunk (transposed)
        if (kg0 < IN_DIM) {
            #pragma unroll
            for (int j = 0; j < 2; ++j) {
                int idx = tid + j * 256;
                int nl = idx >> 3, kk = (idx & 7) * 4;
                int n = base + nl;
                float4 v = (n < N_NODES)
                    ? ((const float4*)(xin + (size_t)n * IN_DIM + kg0))[idx & 7]
                    : make_float4(0.f, 0.f, 0.f, 0.f);
                aS[kk + 0][nl] = v.x;
                aS[kk + 1][nl] = v.y;
                aS[kk + 2][nl] = v.z;
                aS[kk + 3][nl] = v.w;
            }
        } else {
            #pragma unroll
            for (int j = 0; j < 8; ++j) {
                int idx = tid + j * 256;
                int kk = idx >> 6, nl = idx & 63;
                int kg = kg0 + kk - IN_DIM;
                aS[kk][nl] = cosf(tS[nl] * omega[kg] + phase[kg]);
            }
        }
        __syncthreads();

        #pragma unroll
        for (int k = 0; k < KC; ++k) {
            const float4 av = *(const float4*)&aS[k][ty * 4];
            const float4 wv = *(const float4*)&wS[k][tx * 4];
            acc[0][0] = fmaf(av.x, wv.x, acc[0][0]);
            acc[0][1] = fmaf(av.x, wv.y, acc[0][1]);
            acc[0][2] = fmaf(av.x, wv.z, acc[0][2]);
            acc[0][3] = fmaf(av.x, wv.w, acc[0][3]);
            acc[1][0] = fmaf(av.y, wv.x, acc[1][0]);
            acc[1][1] = fmaf(av.y, wv.y, acc[1][1]);
            acc[1][2] = fmaf(av.y, wv.z, acc[1][2]);
            acc[1][3] = fmaf(av.y, wv.w, acc[1][3]);
            acc[2][0] = fmaf(av.z, wv.x, acc[2][0]);
            acc[2][1] = fmaf(av.z, wv.y, acc[2][1]);
            acc[2][2] = fmaf(av.z, wv.z, acc[2][2]);
            acc[2][3] = fmaf(av.z, wv.w, acc[2][3]);
            acc[3][0] = fmaf(av.w, wv.x, acc[3][0]);
            acc[3][1] = fmaf(av.w, wv.y, acc[3][1]);
            acc[3][2] = fmaf(av.w, wv.z, acc[3][2]);
            acc[3][3] = fmaf(av.w, wv.w, acc[3][3]);
        }
    }

    // epilogue: hfeat16 stores (bf16) + per-head scores (fp32)
    const float4 as = ((const float4*)asrc)[tx];
    const float4 ad = ((const float4*)adst)[tx];
    #pragma unroll
    for (int j = 0; j < 4; ++j) {
        const int n = base + ty * 4 + j;
        if (n < N_NODES) {
            ushort4 o;
            o.x = f2bf(acc[j][0]); o.y = f2bf(acc[j][1]);
            o.z = f2bf(acc[j][2]); o.w = f2bf(acc[j][3]);
            *(ushort4*)(hfeat16 + (size_t)n * 64 + tx * 4) = o;
        }
        float vs = acc[j][0] * as.x + acc[j][1] * as.y
                 + acc[j][2] * as.z + acc[j][3] * as.w;
        float vd = acc[j][0] * ad.x + acc[j][1] * ad.y
                 + acc[j][2] * ad.z + acc[j][3] * ad.w;
        vs += __shfl_xor(vs, 1, 64); vs += __shfl_xor(vs, 2, 64);
        vd += __shfl_xor(vd, 1, 64); vd += __shfl_xor(vd, 2, 64);
        if ((tx & 3) == 0 && n < N_NODES) {
            s_src[n * 4 + (tx >> 2)] = vs * LOG2E;   // exp2 domain
            s_dst[n * 4 + (tx >> 2)] = vd * LOG2E;
        }
    }
}

// ---------------- CSR build: two-level bucket sort ----------------
// Bucket = dst>>8 (196 buckets x 256 nodes). All random writes are confined
// to windows owned by a SINGLE block (single CU / single L2) -> structural
// write merging, no dependence on block->XCD mapping.

// count bucket sizes (LDS hist); dst scanned int4 NON-TEMPORAL (read-once)
__global__ __launch_bounds__(256) void bhist_kernel(
    const int* __restrict__ dst, int* __restrict__ bcnt)
{
    __shared__ int c[NBK];
    for (int t = threadIdx.x; t < NBK; t += 256) c[t] = 0;
    __syncthreads();
    const int b4 = blockIdx.x * (BIN_CHUNK / 4);
    const int e4n = N_EDGES / 4;       // E % 4 == 0
    const vint4* d4p = (const vint4*)dst;
    #pragma unroll
    for (int q = 0; q < BIN_CHUNK / 4 / 256; ++q) {
        int i4 = b4 + q * 256 + threadIdx.x;
        if (i4 < e4n) {
            vint4 d4 = __builtin_nontemporal_load(d4p + i4);
            atomicAdd(&c[d4.x >> 8], 1);
            atomicAdd(&c[d4.y >> 8], 1);
            atomicAdd(&c[d4.z >> 8], 1);
            atomicAdd(&c[d4.w >> 8], 1);
        }
    }
    __syncthreads();
    for (int t = threadIdx.x; t < NBK; t += 256)
        if (c[t]) atomicAdd(bcnt + t, c[t]);
}

// exclusive scan of bucket counts -> bstart[0..NBK] ; init tails
__global__ __launch_bounds__(256) void bscan_kernel(
    const int* __restrict__ bcnt, int* __restrict__ bstart, int* __restrict__ tail)
{
    __shared__ int s[256];
    const int t = threadIdx.x;
    int v = (t < NBK) ? bcnt[t] : 0;
    s[t] = v;
    __syncthreads();
    #pragma unroll
    for (int off = 1; off < 256; off <<= 1) {
        int u = (t >= off) ? s[t - off] : 0;
        __syncthreads();
        s[t] += u;
        __syncthreads();
    }
    int excl = s[t] - v;
    if (t < NBK) { bstart[t] = excl; tail[t] = excl; }
    if (t == NBK - 1) bstart[NBK] = s[t];
}

// bin edges into bucket regions, TWO-PASS per 4096-edge chunk:
//   pass 1: LDS-hist count (dst int4-NT)
//   reserve: ONE global tail atomic per bucket
//   pass 2: re-read (NT) + LDS cursor rank + append
// All streaming reads NON-TEMPORAL so the ~200 dirty tail lines stay resident
// in this CU's L2 between appends (round-15: temporal reads evicted them ->
// 4.3x write amplification). Larger chunk doubles run length -> fewer
// boundary lines shared between blocks.
__global__ __launch_bounds__(256) void bin_kernel(
    const int* __restrict__ dst, const int* __restrict__ src,
    const float* __restrict__ ew,
    int* __restrict__ tail, int* __restrict__ rdst, int2* __restrict__ rpair)
{
    __shared__ int cnt[NBK];
    __shared__ int gb[NBK];
    const int tid = threadIdx.x;
    const int b4 = blockIdx.x * (BIN_CHUNK / 4);
    const int e4n = N_EDGES / 4;       // E % 4 == 0
    const vint4* d4p = (const vint4*)dst;
    const vint4* s4p = (const vint4*)src;
    const vfloat4* w4p = (const vfloat4*)ew;

    for (int t = tid; t < NBK; t += 256) cnt[t] = 0;
    __syncthreads();

    // pass 1: count
    #pragma unroll
    for (int q = 0; q < BIN_CHUNK / 4 / 256; ++q) {
        int i4 = b4 + q * 256 + tid;
        if (i4 < e4n) {
            vint4 d4 = __builtin_nontemporal_load(d4p + i4);
            atomicAdd(&cnt[d4.x >> 8], 1);
            atomicAdd(&cnt[d4.y >> 8], 1);
            atomicAdd(&cnt[d4.z >> 8], 1);
            atomicAdd(&cnt[d4.w >> 8], 1);
        }
    }
    __syncthreads();

    // reserve global runs; reset cursors
    for (int t = tid; t < NBK; t += 256) {
        gb[t] = cnt[t] ? atomicAdd(tail + t, cnt[t]) : 0;
    }
    __syncthreads();
    for (int t = tid; t < NBK; t += 256) cnt[t] = 0;
    __syncthreads();

    // pass 2: place
    #pragma unroll
    for (int q = 0; q < BIN_CHUNK / 4 / 256; ++q) {
        int i4 = b4 + q * 256 + tid;
        if (i4 < e4n) {
            vint4 d4 = __builtin_nontemporal_load(d4p + i4);
            vint4 s4 = __builtin_nontemporal_load(s4p + i4);
            vfloat4 w4 = __builtin_nontemporal_load(w4p + i4);
            #pragma unroll
            for (int j = 0; j < 4; ++j) {
                const int d = j == 0 ? d4.x : j == 1 ? d4.y : j == 2 ? d4.z : d4.w;
                const int s = j == 0 ? s4.x : j == 1 ? s4.y : j == 2 ? s4.z : s4.w;
                const float w = j == 0 ? w4.x : j == 1 ? w4.y : j == 2 ? w4.z : w4.w;
                const int bk = d >> 8;
                const int r = atomicAdd(&cnt[bk], 1);
                const int pos = gb[bk] + r;
                rdst[pos] = d;
                rpair[pos] = make_int2(s, __float_as_int(w));
            }
        }
    }
}

// one block per bucket: build deg/rowptr locally (LDS hist+scan) then place
// epair via LDS cursors. rpair is read ONCE -> non-temporal (protects the
// epair write window in this CU's L2); rdst is read twice -> temporal.
__global__ __launch_bounds__(256) void place_kernel(
    const int* __restrict__ bstart, const int* __restrict__ rdst,
    const int2* __restrict__ rpair,
    int* __restrict__ deg, int* __restrict__ rowptr, int2* __restrict__ epair)
{
    __shared__ int ldeg[256];
    __shared__ int ls[256];
    __shared__ int lcur[256];
    const int t = threadIdx.x;
    const int b = blockIdx.x;
    const int lo = bstart[b], hi = bstart[b + 1];
    const int nbase = b << 8;

    ldeg[t] = 0;
    __syncthreads();
    for (int i = lo + t; i < hi; i += 256)
        atomicAdd(&ldeg[rdst[i] & 255], 1);
    __syncthreads();

    const int v = ldeg[t];
    ls[t] = v;
    __syncthreads();
    #pragma unroll
    for (int off = 1; off < 256; off <<= 1) {
        int u = (t >= off) ? ls[t - off] : 0;
        __syncthreads();
        ls[t] += u;
        __syncthreads();
    }
    const int excl = ls[t] - v + lo;
    const int n = nbase + t;
    if (n < N_NODES) { rowptr[n] = excl; deg[n] = v; }
    lcur[t] = excl;
    __syncthreads();

    const vint2* rpv = (const vint2*)rpair;
    for (int i = lo + t; i < hi; i += 256) {
        const int d = rdst[i];
        vint2 rp = __builtin_nontemporal_load(rpv + i);
        const int pos = atomicAdd(&lcur[d & 255], 1);
        epair[pos] = make_int2(rp.x, rp.y);
    }
}

// ---------------- fused per-dst aggregation ----------------
// one wave per node; 8 subgroups x 8 lanes, 8 edges in flight; each lane
// holds 8 bf16 features (ONE uint4 = 16B load, unpacked in-register).
// epair read non-temporally. no max-subtraction; exp2 domain.
template<int FINAL>
__global__ __launch_bounds__(256) void aggregate_kernel(
    const int* __restrict__ rowptr, const int* __restrict__ deg,
    const int2* __restrict__ epair,
    const float* __restrict__ s_src, const float* __restrict__ s_dst,
    const unsigned short* __restrict__ hfeat16,
    const float* __restrict__ whead, const float* __restrict__ bhead,
    float* __restrict__ outp)
{
    const int n = blockIdx.x * 4 + (threadIdx.x >> 6);
    if (n >= N_NODES) return;
    const int lane = threadIdx.x & 63;
    const int g = lane >> 3;          // subgroup (edge slot 0..7)
    const int sl = lane & 7;          // feature octet
    const int hh = sl >> 1;           // head of my features
    const float sdst = s_dst[n * 4 + hh];
    const int beg = rowptr[n];
    const int cnt = deg[n];
    const vint2* epv = (const vint2*)epair + beg;
    const vint2 zz = {0, 0};

    float den = 0.f;
    float4 a0 = make_float4(0.f, 0.f, 0.f, 0.f);
    float4 a1 = make_float4(0.f, 0.f, 0.f, 0.f);

    int i = g;
    vint2 ep = (i < cnt) ? __builtin_nontemporal_load(epv + i) : zz;
    while (i < cnt) {
        const int inext = i + 8;
        vint2 epn = (inext < cnt) ? __builtin_nontemporal_load(epv + inext) : zz;
        const int s = ep.x;
        const float w = __int_as_float(ep.y);
        float sc = s_src[(size_t)s * 4 + hh] + sdst;
        sc = fmaxf(sc, 0.2f * sc);                       // leaky relu (log2 domain)
        const float p = __builtin_amdgcn_exp2f(sc) * w;
        const uint4 hv = *(const uint4*)(hfeat16 + (size_t)s * 64 + sl * 8);
        den += p;
        a0.x = fmaf(p, bf_lo(hv.x), a0.x); a0.y = fmaf(p, bf_hi(hv.x), a0.y);
        a0.z = fmaf(p, bf_lo(hv.y), a0.z); a0.w = fmaf(p, bf_hi(hv.y), a0.w);
        a1.x = fmaf(p, bf_lo(hv.z), a1.x); a1.y = fmaf(p, bf_hi(hv.z), a1.y);
        a1.z = fmaf(p, bf_lo(hv.w), a1.z); a1.w = fmaf(p, bf_hi(hv.w), a1.w);
        ep = epn; i = inext;
    }

    // merge 8 subgroups (lane bits 3,4,5)
    #pragma unroll
    for (int off = 8; off <= 32; off <<= 1) {
        den  += __shfl_xor(den, off, 64);
        a0.x += __shfl_xor(a0.x, off, 64); a0.y += __shfl_xor(a0.y, off, 64);
        a0.z += __shfl_xor(a0.z, off, 64); a0.w += __shfl_xor(a0.w, off, 64);
        a1.x += __shfl_xor(a1.x, off, 64); a1.y += __shfl_xor(a1.y, off, 64);
        a1.z += __shfl_xor(a1.z, off, 64); a1.w += __shfl_xor(a1.w, off, 64);
    }

    const float inv = 1.f / (den + 1e-16f);
    if (!FINAL) {
        if (g == 0) {
            float4 v0, v1;
            v0.x = a0.x * inv; v0.x = v0.x > 0.f ? v0.x : expm1f(v0.x);
            v0.y = a0.y * inv; v0.y = v0.y > 0.f ? v0.y : expm1f(v0.y);
            v0.z = a0.z * inv; v0.z = v0.z > 0.f ? v0.z : expm1f(v0.z);
            v0.w = a0.w * inv; v0.w = v0.w > 0.f ? v0.w : expm1f(v0.w);
            v1.x = a1.x * inv; v1.x = v1.x > 0.f ? v1.x : expm1f(v1.x);
            v1.y = a1.y * inv; v1.y = v1.y > 0.f ? v1.y : expm1f(v1.y);
            v1.z = a1.z * inv; v1.z = v1.z > 0.f ? v1.z : expm1f(v1.z);
            v1.w = a1.w * inv; v1.w = v1.w > 0.f ? v1.w : expm1f(v1.w);
            float4* op = (float4*)(outp + (size_t)n * 64 + sl * 8);
            op[0] = v0; op[1] = v1;
        }
    } else {
        const float4* wp = (const float4*)(whead + sl * 8);
        const float4 w0 = wp[0], w1 = wp[1];
        float v = (a0.x * w0.x + a0.y * w0.y + a0.z * w0.z + a0.w * w0.w
                 + a1.x * w1.x + a1.y * w1.y + a1.z * w1.z + a1.w * w1.w) * inv;
        #pragma unroll
        for (int off = 1; off <= 4; off <<= 1) v += __shfl_xor(v, off, 64);
        if (lane == 0) outp[n] = v + bhead[0];
    }
}

extern "C" void kernel_launch(void* const* d_in, const int* in_sizes, int n_in,
                              void* d_out, int out_size, void* d_ws, size_t ws_size,
                              hipStream_t stream) {
    const float* x      = (const float*)d_in[0];
    const int*   eidx   = (const int*)d_in[1];
    const float* ew     = (const float*)d_in[2];
    const float* tim    = (const float*)d_in[3];
    const float* omega0 = (const float*)d_in[4];
    const float* phase0 = (const float*)d_in[5];
    const float* W0     = (const float*)d_in[6];
    const float* asrc0  = (const float*)d_in[7];
    const float* adst0  = (const float*)d_in[8];
    const float* omega1 = (const float*)d_in[9];
    const float* phase1 = (const float*)d_in[10];
    const float* W1     = (const float*)d_in[11];
    const float* asrc1  = (const float*)d_in[12];
    const float* adst1  = (const float*)d_in[13];
    const float* Whead  = (const float*)d_in[14];
    const float* bhead  = (const float*)d_in[15];
    float* out = (float*)d_out;

    const int* src = eidx;
    const int* dst = eidx + N_EDGES;

    float* ws = (float*)d_ws;
    unsigned short* hfeat16 = (unsigned short*)ws;   // N*64 ushorts (6.4MB)
    float* x1    = (float*)(hfeat16 + (size_t)N_NODES * 64);  // N*64 floats
    float* s_src = x1    + (size_t)N_NODES * 64;     // N*4
    float* s_dst = s_src + (size_t)N_NODES * 4;      // N*4
    int2* epair  = (int2*)(s_dst + (size_t)N_NODES * 4);   // E int2
    int* deg     = (int*)(epair + (size_t)N_EDGES);  // N
    int* rowptr  = deg + N_NODES;                    // N
    int* bcnt    = rowptr + N_NODES;                 // NBK
    int* bstart  = bcnt + NBK;                       // NBK+1
    int* tail    = bstart + NBK + 1;                 // NBK
    // record arrays alias dead buffers: consumed by place() before their
    // aliases are written (hfeat16 by transform<128>, x1 by aggregate<0>).
    // E*4B == N*64*2B exactly (6.4MB); E*8B == N*64*4B (12.8MB).
    int*  rdst  = (int*)hfeat16;                     // E ints
    int2* rpair = (int2*)x1;                         // E int2

    const int tf_grid  = (N_NODES + 63) / 64;        // 782
    const int agg_grid = (N_NODES + 3) / 4;

    // ---- CSR build (two-level bucket sort; shared by both layers) ----
    hipMemsetAsync(bcnt, 0, NBK * sizeof(int), stream);
    bhist_kernel<<<BIN_GRID, 256, 0, stream>>>(dst, bcnt);
    bscan_kernel<<<1, 256, 0, stream>>>(bcnt, bstart, tail);
    bin_kernel<<<BIN_GRID, 256, 0, stream>>>(dst, src, ew, tail, rdst, rpair);
    place_kernel<<<NBK, 256, 0, stream>>>(bstart, rdst, rpair, deg, rowptr, epair);

    // ---- layer 0 ----
    transform_kernel<128><<<tf_grid, 256, 0, stream>>>(
        x, tim, omega0, phase0, W0, asrc0, adst0, hfeat16, s_src, s_dst);
    aggregate_kernel<0><<<agg_grid, 256, 0, stream>>>(
        rowptr, deg, epair, s_src, s_dst, hfeat16, Whead, bhead, x1);

    // ---- layer 1 (+ fused linear head) ----
    transform_kernel<64><<<tf_grid, 256, 0, stream>>>(
        x1, tim, omega1, phase1, W1, asrc1, adst1, hfeat16, s_src, s_dst);
    aggregate_kernel<1><<<agg_grid, 256, 0, stream>>>(
        rowptr, deg, epair, s_src, s_dst, hfeat16, Whead, bhead, out);
}

// Round 17
// 221.185 us; speedup vs baseline: 1.2646x; 1.1032x over previous
//
#include <hip/hip_runtime.h>
#include <hip/hip_bf16.h>
#include <math.h>

#define N_NODES 50000
#define N_EDGES 1600000
#define TE 64
#define LOG2E 1.44269504088896340736f
#define NBK 196            // dst buckets: bucket = dst >> 8 (256 nodes each)
#define BIN_CHUNK 4096
#define BIN_GRID ((N_EDGES + BIN_CHUNK - 1) / BIN_CHUNK)   // 391

typedef int vint2 __attribute__((ext_vector_type(2)));
typedef int vint4 __attribute__((ext_vector_type(4)));
typedef float vfloat4 __attribute__((ext_vector_type(4)));
typedef unsigned int uint;

__device__ __forceinline__ unsigned short f2bf(float f) {
    uint u = __float_as_uint(f);
    return (unsigned short)((u + 0x7fffu + ((u >> 16) & 1u)) >> 16);   // RNE
}
__device__ __forceinline__ float bf_lo(uint u) { return __uint_as_float(u << 16); }
__device__ __forceinline__ float bf_hi(uint u) { return __uint_as_float(u & 0xffff0000u); }

// ---------------- node transform ----------------
// h = concat(x, cos(t*omega+phase)) @ W. FINAL=0: h stored bf16 + s_src/s_dst.
// FINAL=1 (last layer): h itself is never needed downstream — only the
// head-projected per-head scalar hw[n,h] = sum_d h[n,h,d]*Whead[h,d] (the
// head projection commutes with the alpha-weighted edge sum). Writes
// l1tab[n] = {s_src[4] (exp2 domain), hw[4]} (32B record) + s_dst; skips
// hfeat16 entirely.
template<int IN_DIM, int FINAL>
__global__ __launch_bounds__(256) void transform_kernel(
    const float* __restrict__ xin, const float* __restrict__ tim,
    const float* __restrict__ omega, const float* __restrict__ phase,
    const float* __restrict__ W, const float* __restrict__ asrc,
    const float* __restrict__ adst, const float* __restrict__ whead,
    unsigned short* __restrict__ hfeat16,
    float* __restrict__ s_src, float* __restrict__ s_dst,
    float* __restrict__ l1tab)
{
    constexpr int K = IN_DIM + TE;
    constexpr int KC = 32;             // k-chunk
    constexpr int NCH = K / KC;
    constexpr int BN = 64;             // nodes per block
    __shared__ float aS[KC][68];       // transposed a-chunk (padded row: 272B)
    __shared__ float wS[KC][64];
    __shared__ float tS[BN];

    const int tid = threadIdx.x;
    const int base = blockIdx.x * BN;

    if (tid < BN) {
        int n = base + tid;
        tS[tid] = (n < N_NODES) ? tim[n] : 0.f;
    }

    const int ty = tid >> 4;           // node quad: nodes ty*4 .. ty*4+3
    const int tx = tid & 15;           // col slot: cols tx*4 .. tx*4+3

    float acc[4][4] = {};

    for (int ch = 0; ch < NCH; ++ch) {
        const int kg0 = ch * KC;
        __syncthreads();               // previous chunk fully consumed

        // stage W chunk: 32x64 floats = 512 float4, 2 per thread (coalesced)
        #pragma unroll
        for (int j = 0; j < 2; ++j) {
            int idx = tid + j * 256;                    // float4 index
            int kk = idx >> 4, c4 = idx & 15;
            *(float4*)&wS[kk][c4 * 4] =
                ((const float4*)(W + (size_t)(kg0 + kk) * 64))[c4];
        }

        // stage a chunk (transposed)
        if (kg0 < IN_DIM) {
            #pragma unroll
            for (int j = 0; j < 2; ++j) {
                int idx = tid + j * 256;
                int nl = idx >> 3, kk = (idx & 7) * 4;
                int n = base + nl;
                float4 v = (n < N_NODES)
                    ? ((const float4*)(xin + (size_t)n * IN_DIM + kg0))[idx & 7]
                    : make_float4(0.f, 0.f, 0.f, 0.f);
                aS[kk + 0][nl] = v.x;
                aS[kk + 1][nl] = v.y;
                aS[kk + 2][nl] = v.z;
                aS[kk + 3][nl] = v.w;
            }
        } else {
            #pragma unroll
            for (int j = 0; j < 8; ++j) {
                int idx = tid + j * 256;
                int kk = idx >> 6, nl = idx & 63;
                int kg = kg0 + kk - IN_DIM;
                aS[kk][nl] = cosf(tS[nl] * omega[kg] + phase[kg]);
            }
        }
        __syncthreads();

        #pragma unroll
        for (int k = 0; k < KC; ++k) {
            const float4 av = *(const float4*)&aS[k][ty * 4];
            const float4 wv = *(const float4*)&wS[k][tx * 4];
            acc[0][0] = fmaf(av.x, wv.x, acc[0][0]);
            acc[0][1] = fmaf(av.x, wv.y, acc[0][1]);
            acc[0][2] = fmaf(av.x, wv.z, acc[0][2]);
            acc[0][3] = fmaf(av.x, wv.w, acc[0][3]);
            acc[1][0] = fmaf(av.y, wv.x, acc[1][0]);
            acc[1][1] = fmaf(av.y, wv.y, acc[1][1]);
            acc[1][2] = fmaf(av.y, wv.z, acc[1][2]);
            acc[1][3] = fmaf(av.y, wv.w, acc[1][3]);
            acc[2][0] = fmaf(av.z, wv.x, acc[2][0]);
            acc[2][1] = fmaf(av.z, wv.y, acc[2][1]);
            acc[2][2] = fmaf(av.z, wv.z, acc[2][2]);
            acc[2][3] = fmaf(av.z, wv.w, acc[2][3]);
            acc[3][0] = fmaf(av.w, wv.x, acc[3][0]);
            acc[3][1] = fmaf(av.w, wv.y, acc[3][1]);
            acc[3][2] = fmaf(av.w, wv.z, acc[3][2]);
            acc[3][3] = fmaf(av.w, wv.w, acc[3][3]);
        }
    }

    // epilogue: per-head scores (+ hw head-dot if FINAL; else bf16 h stores)
    const float4 as = ((const float4*)asrc)[tx];
    const float4 ad = ((const float4*)adst)[tx];
    float4 wh = make_float4(0.f, 0.f, 0.f, 0.f);
    if (FINAL) wh = ((const float4*)whead)[tx];
    #pragma unroll
    for (int j = 0; j < 4; ++j) {
        const int n = base + ty * 4 + j;
        if (!FINAL && n < N_NODES) {
            ushort4 o;
            o.x = f2bf(acc[j][0]); o.y = f2bf(acc[j][1]);
            o.z = f2bf(acc[j][2]); o.w = f2bf(acc[j][3]);
            *(ushort4*)(hfeat16 + (size_t)n * 64 + tx * 4) = o;
        }
        float vs = acc[j][0] * as.x + acc[j][1] * as.y
                 + acc[j][2] * as.z + acc[j][3] * as.w;
        float vd = acc[j][0] * ad.x + acc[j][1] * ad.y
                 + acc[j][2] * ad.z + acc[j][3] * ad.w;
        float vw = 0.f;
        if (FINAL)
            vw = acc[j][0] * wh.x + acc[j][1] * wh.y
               + acc[j][2] * wh.z + acc[j][3] * wh.w;
        vs += __shfl_xor(vs, 1, 64); vs += __shfl_xor(vs, 2, 64);
        vd += __shfl_xor(vd, 1, 64); vd += __shfl_xor(vd, 2, 64);
        if (FINAL) { vw += __shfl_xor(vw, 1, 64); vw += __shfl_xor(vw, 2, 64); }
        if ((tx & 3) == 0 && n < N_NODES) {
            if (FINAL) {
                l1tab[(size_t)n * 8 + (tx >> 2)]     = vs * LOG2E;
                l1tab[(size_t)n * 8 + 4 + (tx >> 2)] = vw;
                s_dst[n * 4 + (tx >> 2)] = vd * LOG2E;
            } else {
                s_src[n * 4 + (tx >> 2)] = vs * LOG2E;   // exp2 domain
                s_dst[n * 4 + (tx >> 2)] = vd * LOG2E;
            }
        }
    }
}

// ---------------- CSR build: two-level bucket sort ----------------
// Bucket = dst>>8 (196 buckets x 256 nodes). All random writes are confined
// to windows owned by a SINGLE block (single CU / single L2) -> structural
// write merging, no dependence on block->XCD mapping.

__global__ __launch_bounds__(256) void bhist_kernel(
    const int* __restrict__ dst, int* __restrict__ bcnt)
{
    __shared__ int c[NBK];
    for (int t = threadIdx.x; t < NBK; t += 256) c[t] = 0;
    __syncthreads();
    const int b4 = blockIdx.x * (BIN_CHUNK / 4);
    const int e4n = N_EDGES / 4;       // E % 4 == 0
    const vint4* d4p = (const vint4*)dst;
    #pragma unroll
    for (int q = 0; q < BIN_CHUNK / 4 / 256; ++q) {
        int i4 = b4 + q * 256 + threadIdx.x;
        if (i4 < e4n) {
            vint4 d4 = __builtin_nontemporal_load(d4p + i4);
            atomicAdd(&c[d4.x >> 8], 1);
            atomicAdd(&c[d4.y >> 8], 1);
            atomicAdd(&c[d4.z >> 8], 1);
            atomicAdd(&c[d4.w >> 8], 1);
        }
    }
    __syncthreads();
    for (int t = threadIdx.x; t < NBK; t += 256)
        if (c[t]) atomicAdd(bcnt + t, c[t]);
}

__global__ __launch_bounds__(256) void bscan_kernel(
    const int* __restrict__ bcnt, int* __restrict__ bstart, int* __restrict__ tail)
{
    __shared__ int s[256];
    const int t = threadIdx.x;
    int v = (t < NBK) ? bcnt[t] : 0;
    s[t] = v;
    __syncthreads();
    #pragma unroll
    for (int off = 1; off < 256; off <<= 1) {
        int u = (t >= off) ? s[t - off] : 0;
        __syncthreads();
        s[t] += u;
        __syncthreads();
    }
    int excl = s[t] - v;
    if (t < NBK) { bstart[t] = excl; tail[t] = excl; }
    if (t == NBK - 1) bstart[NBK] = s[t];
}

__global__ __launch_bounds__(256) void bin_kernel(
    const int* __restrict__ dst, const int* __restrict__ src,
    const float* __restrict__ ew,
    int* __restrict__ tail, int* __restrict__ rdst, int2* __restrict__ rpair)
{
    __shared__ int cnt[NBK];
    __shared__ int gb[NBK];
    const int tid = threadIdx.x;
    const int b4 = blockIdx.x * (BIN_CHUNK / 4);
    const int e4n = N_EDGES / 4;       // E % 4 == 0
    const vint4* d4p = (const vint4*)dst;
    const vint4* s4p = (const vint4*)src;
    const vfloat4* w4p = (const vfloat4*)ew;

    for (int t = tid; t < NBK; t += 256) cnt[t] = 0;
    __syncthreads();

    // pass 1: count
    #pragma unroll
    for (int q = 0; q < BIN_CHUNK / 4 / 256; ++q) {
        int i4 = b4 + q * 256 + tid;
        if (i4 < e4n) {
            vint4 d4 = __builtin_nontemporal_load(d4p + i4);
            atomicAdd(&cnt[d4.x >> 8], 1);
            atomicAdd(&cnt[d4.y >> 8], 1);
            atomicAdd(&cnt[d4.z >> 8], 1);
            atomicAdd(&cnt[d4.w >> 8], 1);
        }
    }
    __syncthreads();

    // reserve global runs; reset cursors
    for (int t = tid; t < NBK; t += 256) {
        gb[t] = cnt[t] ? atomicAdd(tail + t, cnt[t]) : 0;
    }
    __syncthreads();
    for (int t = tid; t < NBK; t += 256) cnt[t] = 0;
    __syncthreads();

    // pass 2: place
    #pragma unroll
    for (int q = 0; q < BIN_CHUNK / 4 / 256; ++q) {
        int i4 = b4 + q * 256 + tid;
        if (i4 < e4n) {
            vint4 d4 = __builtin_nontemporal_load(d4p + i4);
            vint4 s4 = __builtin_nontemporal_load(s4p + i4);
            vfloat4 w4 = __builtin_nontemporal_load(w4p + i4);
            #pragma unroll
            for (int j = 0; j < 4; ++j) {
                const int d = j == 0 ? d4.x : j == 1 ? d4.y : j == 2 ? d4.z : d4.w;
                const int s = j == 0 ? s4.x : j == 1 ? s4.y : j == 2 ? s4.z : s4.w;
                const float w = j == 0 ? w4.x : j == 1 ? w4.y : j == 2 ? w4.z : w4.w;
                const int bk = d >> 8;
                const int r = atomicAdd(&cnt[bk], 1);
                const int pos = gb[bk] + r;
                rdst[pos] = d;
                rpair[pos] = make_int2(s, __float_as_int(w));
            }
        }
    }
}

__global__ __launch_bounds__(256) void place_kernel(
    const int* __restrict__ bstart, const int* __restrict__ rdst,
    const int2* __restrict__ rpair,
    int* __restrict__ deg, int* __restrict__ rowptr, int2* __restrict__ epair)
{
    __shared__ int ldeg[256];
    __shared__ int ls[256];
    __shared__ int lcur[256];
    const int t = threadIdx.x;
    const int b = blockIdx.x;
    const int lo = bstart[b], hi = bstart[b + 1];
    const int nbase = b << 8;

    ldeg[t] = 0;
    __syncthreads();
    for (int i = lo + t; i < hi; i += 256)
        atomicAdd(&ldeg[rdst[i] & 255], 1);
    __syncthreads();

    const int v = ldeg[t];
    ls[t] = v;
    __syncthreads();
    #pragma unroll
    for (int off = 1; off < 256; off <<= 1) {
        int u = (t >= off) ? ls[t - off] : 0;
        __syncthreads();
        ls[t] += u;
        __syncthreads();
    }
    const int excl = ls[t] - v + lo;
    const int n = nbase + t;
    if (n < N_NODES) { rowptr[n] = excl; deg[n] = v; }
    lcur[t] = excl;
    __syncthreads();

    const vint2* rpv = (const vint2*)rpair;
    for (int i = lo + t; i < hi; i += 256) {
        const int d = rdst[i];
        vint2 rp = __builtin_nontemporal_load(rpv + i);
        const int pos = atomicAdd(&lcur[d & 255], 1);
        epair[pos] = make_int2(rp.x, rp.y);
    }
}

// ---------------- layer-0 aggregation (full 64-dim output) ----------------
// one wave per node; 8 subgroups x 8 lanes, 8 edges in flight; each lane
// holds 8 bf16 features (ONE uint4 = 16B load, unpacked in-register).
// epair read non-temporally. no max-subtraction; exp2 domain.
__global__ __launch_bounds__(256) void aggregate_kernel(
    const int* __restrict__ rowptr, const int* __restrict__ deg,
    const int2* __restrict__ epair,
    const float* __restrict__ s_src, const float* __restrict__ s_dst,
    const unsigned short* __restrict__ hfeat16,
    float* __restrict__ outp)
{
    const int n = blockIdx.x * 4 + (threadIdx.x >> 6);
    if (n >= N_NODES) return;
    const int lane = threadIdx.x & 63;
    const int g = lane >> 3;          // subgroup (edge slot 0..7)
    const int sl = lane & 7;          // feature octet
    const int hh = sl >> 1;           // head of my features
    const float sdst = s_dst[n * 4 + hh];
    const int beg = rowptr[n];
    const int cnt = deg[n];
    const vint2* epv = (const vint2*)epair + beg;
    const vint2 zz = {0, 0};

    float den = 0.f;
    float4 a0 = make_float4(0.f, 0.f, 0.f, 0.f);
    float4 a1 = make_float4(0.f, 0.f, 0.f, 0.f);

    int i = g;
    vint2 ep = (i < cnt) ? __builtin_nontemporal_load(epv + i) : zz;
    while (i < cnt) {
        const int inext = i + 8;
        vint2 epn = (inext < cnt) ? __builtin_nontemporal_load(epv + inext) : zz;
        const int s = ep.x;
        const float w = __int_as_float(ep.y);
        float sc = s_src[(size_t)s * 4 + hh] + sdst;
        sc = fmaxf(sc, 0.2f * sc);                       // leaky relu (log2 domain)
        const float p = __builtin_amdgcn_exp2f(sc) * w;
        const uint4 hv = *(const uint4*)(hfeat16 + (size_t)s * 64 + sl * 8);
        den += p;
        a0.x = fmaf(p, bf_lo(hv.x), a0.x); a0.y = fmaf(p, bf_hi(hv.x), a0.y);
        a0.z = fmaf(p, bf_lo(hv.y), a0.z); a0.w = fmaf(p, bf_hi(hv.y), a0.w);
        a1.x = fmaf(p, bf_lo(hv.z), a1.x); a1.y = fmaf(p, bf_hi(hv.z), a1.y);
        a1.z = fmaf(p, bf_lo(hv.w), a1.z); a1.w = fmaf(p, bf_hi(hv.w), a1.w);
        ep = epn; i = inext;
    }

    // merge 8 subgroups (lane bits 3,4,5)
    #pragma unroll
    for (int off = 8; off <= 32; off <<= 1) {
        den  += __shfl_xor(den, off, 64);
        a0.x += __shfl_xor(a0.x, off, 64); a0.y += __shfl_xor(a0.y, off, 64);
        a0.z += __shfl_xor(a0.z, off, 64); a0.w += __shfl_xor(a0.w, off, 64);
        a1.x += __shfl_xor(a1.x, off, 64); a1.y += __shfl_xor(a1.y, off, 64);
        a1.z += __shfl_xor(a1.z, off, 64); a1.w += __shfl_xor(a1.w, off, 64);
    }

    const float inv = 1.f / (den + 1e-16f);
    if (g == 0) {
        float4 v0, v1;
        v0.x = a0.x * inv; v0.x = v0.x > 0.f ? v0.x : expm1f(v0.x);
        v0.y = a0.y * inv; v0.y = v0.y > 0.f ? v0.y : expm1f(v0.y);
        v0.z = a0.z * inv; v0.z = v0.z > 0.f ? v0.z : expm1f(v0.z);
        v0.w = a0.w * inv; v0.w = v0.w > 0.f ? v0.w : expm1f(v0.w);
        v1.x = a1.x * inv; v1.x = v1.x > 0.f ? v1.x : expm1f(v1.x);
        v1.y = a1.y * inv; v1.y = v1.y > 0.f ? v1.y : expm1f(v1.y);
        v1.z = a1.z * inv; v1.z = v1.z > 0.f ? v1.z : expm1f(v1.z);
        v1.w = a1.w * inv; v1.w = v1.w > 0.f ? v1.w : expm1f(v1.w);
        float4* op = (float4*)(outp + (size_t)n * 64 + sl * 8);
        op[0] = v0; op[1] = v1;
    }
}

// ---------------- layer-1 head-collapsed aggregation ----------------
// out[n] = sum_h (sum_e p_eh * hw[s_e,h]) / den_h + b. Per edge only a 32B
// l1tab record {s_src[4], hw[4]} is gathered (vs 144B for full features).
// one wave per node; 16 subgroups x 4 lanes; lane = (edge slot g, head h).
__global__ __launch_bounds__(256) void head_aggregate_kernel(
    const int* __restrict__ rowptr, const int* __restrict__ deg,
    const int2* __restrict__ epair,
    const float* __restrict__ l1tab, const float* __restrict__ s_dst,
    const float* __restrict__ bhead, float* __restrict__ outp)
{
    const int n = blockIdx.x * 4 + (threadIdx.x >> 6);
    if (n >= N_NODES) return;
    const int lane = threadIdx.x & 63;
    const int g = lane >> 2;          // subgroup (edge slot 0..15)
    const int h = lane & 3;           // head
    const float sdst = s_dst[n * 4 + h];
    const int beg = rowptr[n];
    const int cnt = deg[n];
    const vint2* epv = (const vint2*)epair + beg;
    const vint2 zz = {0, 0};

    float den = 0.f, num = 0.f;

    int i = g;
    vint2 ep = (i < cnt) ? __builtin_nontemporal_load(epv + i) : zz;
    while (i < cnt) {
        const int inext = i + 16;
        vint2 epn = (inext < cnt) ? __builtin_nontemporal_load(epv + inext) : zz;
        const int s = ep.x;
        const float w = __int_as_float(ep.y);
        const float* rec = l1tab + (size_t)s * 8;
        float sc = rec[h] + sdst;
        sc = fmaxf(sc, 0.2f * sc);                       // leaky relu (log2 domain)
        const float p = __builtin_amdgcn_exp2f(sc) * w;
        den += p;
        num = fmaf(p, rec[4 + h], num);
        ep = epn; i = inext;
    }

    // merge 16 subgroups (lane bits 2..5)
    #pragma unroll
    for (int off = 4; off <= 32; off <<= 1) {
        den += __shfl_xor(den, off, 64);
        num += __shfl_xor(num, off, 64);
    }

    float v = num / (den + 1e-16f);
    v += __shfl_xor(v, 1, 64);
    v += __shfl_xor(v, 2, 64);
    if (lane == 0) outp[n] = v + bhead[0];
}

extern "C" void kernel_launch(void* const* d_in, const int* in_sizes, int n_in,
                              void* d_out, int out_size, void* d_ws, size_t ws_size,
                              hipStream_t stream) {
    const float* x      = (const float*)d_in[0];
    const int*   eidx   = (const int*)d_in[1];
    const float* ew     = (const float*)d_in[2];
    const float* tim    = (const float*)d_in[3];
    const float* omega0 = (const float*)d_in[4];
    const float* phase0 = (const float*)d_in[5];
    const float* W0     = (const float*)d_in[6];
    const float* asrc0  = (const float*)d_in[7];
    const float* adst0  = (const float*)d_in[8];
    const float* omega1 = (const float*)d_in[9];
    const float* phase1 = (const float*)d_in[10];
    const float* W1     = (const float*)d_in[11];
    const float* asrc1  = (const float*)d_in[12];
    const float* adst1  = (const float*)d_in[13];
    const float* Whead  = (const float*)d_in[14];
    const float* bhead  = (const float*)d_in[15];
    float* out = (float*)d_out;

    const int* src = eidx;
    const int* dst = eidx + N_EDGES;

    float* ws = (float*)d_ws;
    unsigned short* hfeat16 = (unsigned short*)ws;   // N*64 ushorts (6.4MB)
    float* x1    = (float*)(hfeat16 + (size_t)N_NODES * 64);  // N*64 floats
    float* s_src = x1    + (size_t)N_NODES * 64;     // N*4
    float* s_dst = s_src + (size_t)N_NODES * 4;      // N*4
    int2* epair  = (int2*)(s_dst + (size_t)N_NODES * 4);   // E int2
    int* deg     = (int*)(epair + (size_t)N_EDGES);  // N
    int* rowptr  = deg + N_NODES;                    // N
    int* bcnt    = rowptr + N_NODES;                 // NBK
    int* bstart  = bcnt + NBK;                       // NBK+1
    int* tail    = bstart + NBK + 1;                 // NBK
    float* l1tab = (float*)(tail + NBK);             // N*8 floats (1.6MB)
    // record arrays alias dead buffers: consumed by place() before their
    // aliases are written (hfeat16 by transform<128>, x1 by aggregate).
    // E*4B == N*64*2B exactly (6.4MB); E*8B == N*64*4B (12.8MB).
    int*  rdst  = (int*)hfeat16;                     // E ints
    int2* rpair = (int2*)x1;                         // E int2

    const int tf_grid  = (N_NODES + 63) / 64;        // 782
    const int agg_grid = (N_NODES + 3) / 4;

    // ---- CSR build (two-level bucket sort; shared by both layers) ----
    hipMemsetAsync(bcnt, 0, NBK * sizeof(int), stream);
    bhist_kernel<<<BIN_GRID, 256, 0, stream>>>(dst, bcnt);
    bscan_kernel<<<1, 256, 0, stream>>>(bcnt, bstart, tail);
    bin_kernel<<<BIN_GRID, 256, 0, stream>>>(dst, src, ew, tail, rdst, rpair);
    place_kernel<<<NBK, 256, 0, stream>>>(bstart, rdst, rpair, deg, rowptr, epair);

    // ---- layer 0 ----
    transform_kernel<128, 0><<<tf_grid, 256, 0, stream>>>(
        x, tim, omega0, phase0, W0, asrc0, adst0, Whead,
        hfeat16, s_src, s_dst, l1tab);
    aggregate_kernel<<<agg_grid, 256, 0, stream>>>(
        rowptr, deg, epair, s_src, s_dst, hfeat16, x1);

    // ---- layer 1 (head-collapsed: h@Whead folded into per-node hw) ----
    transform_kernel<64, 1><<<tf_grid, 256, 0, stream>>>(
        x1, tim, omega1, phase1, W1, asrc1, adst1, Whead,
        hfeat16, s_src, s_dst, l1tab);
    head_aggregate_kernel<<<agg_grid, 256, 0, stream>>>(
        rowptr, deg, epair, l1tab, s_dst, bhead, out);
}

// Round 18
// 209.068 us; speedup vs baseline: 1.3379x; 1.0580x over previous
//
#include <hip/hip_runtime.h>
#include <hip/hip_bf16.h>
#include <math.h>

#define N_NODES 50000
#define N_EDGES 1600000
#define TE 64
#define LOG2E 1.44269504088896340736f
#define NBK 196            // dst buckets: bucket = dst >> 8 (256 nodes each)
#define BIN_CHUNK 8192
#define BIN_GRID ((N_EDGES + BIN_CHUNK - 1) / BIN_CHUNK)   // 196

typedef int vint2 __attribute__((ext_vector_type(2)));
typedef int vint4 __attribute__((ext_vector_type(4)));
typedef float vfloat4 __attribute__((ext_vector_type(4)));
typedef unsigned int uint;

__device__ __forceinline__ unsigned short f2bf(float f) {
    uint u = __float_as_uint(f);
    return (unsigned short)((u + 0x7fffu + ((u >> 16) & 1u)) >> 16);   // RNE
}
__device__ __forceinline__ float bf_lo(uint u) { return __uint_as_float(u << 16); }
__device__ __forceinline__ float bf_hi(uint u) { return __uint_as_float(u & 0xffff0000u); }

// ---------------- node transform ----------------
// h = concat(x, cos(t*omega+phase)) @ W. FINAL=0: h stored bf16 + s_src/s_dst.
// FINAL=1: only the head-projected scalar hw[n,h] and s_src are needed
// downstream (head projection commutes with the alpha-weighted edge sum);
// writes interleaved l1tab[n] = {s0,hw0,s1,hw1,...} (32B record) + s_dst.
template<int IN_DIM, int FINAL>
__global__ __launch_bounds__(256) void transform_kernel(
    const float* __restrict__ xin, const float* __restrict__ tim,
    const float* __restrict__ omega, const float* __restrict__ phase,
    const float* __restrict__ W, const float* __restrict__ asrc,
    const float* __restrict__ adst, const float* __restrict__ whead,
    unsigned short* __restrict__ hfeat16,
    float* __restrict__ s_src, float* __restrict__ s_dst,
    float* __restrict__ l1tab)
{
    constexpr int K = IN_DIM + TE;
    constexpr int KC = 32;             // k-chunk
    constexpr int NCH = K / KC;
    constexpr int BN = 64;             // nodes per block
    __shared__ float aS[KC][68];       // transposed a-chunk (padded row: 272B)
    __shared__ float wS[KC][64];
    __shared__ float tS[BN];

    const int tid = threadIdx.x;
    const int base = blockIdx.x * BN;

    if (tid < BN) {
        int n = base + tid;
        tS[tid] = (n < N_NODES) ? tim[n] : 0.f;
    }

    const int ty = tid >> 4;           // node quad: nodes ty*4 .. ty*4+3
    const int tx = tid & 15;           // col slot: cols tx*4 .. tx*4+3

    float acc[4][4] = {};

    for (int ch = 0; ch < NCH; ++ch) {
        const int kg0 = ch * KC;
        __syncthreads();               // previous chunk fully consumed

        // stage W chunk: 32x64 floats = 512 float4, 2 per thread (coalesced)
        #pragma unroll
        for (int j = 0; j < 2; ++j) {
            int idx = tid + j * 256;                    // float4 index
            int kk = idx >> 4, c4 = idx & 15;
            *(float4*)&wS[kk][c4 * 4] =
                ((const float4*)(W + (size_t)(kg0 + kk) * 64))[c4];
        }

        // stage a chunk (transposed)
        if (kg0 < IN_DIM) {
            #pragma unroll
            for (int j = 0; j < 2; ++j) {
                int idx = tid + j * 256;
                int nl = idx >> 3, kk = (idx & 7) * 4;
                int n = base + nl;
                float4 v = (n < N_NODES)
                    ? ((const float4*)(xin + (size_t)n * IN_DIM + kg0))[idx & 7]
                    : make_float4(0.f, 0.f, 0.f, 0.f);
                aS[kk + 0][nl] = v.x;
                aS[kk + 1][nl] = v.y;
                aS[kk + 2][nl] = v.z;
                aS[kk + 3][nl] = v.w;
            }
        } else {
            #pragma unroll
            for (int j = 0; j < 8; ++j) {
                int idx = tid + j * 256;
                int kk = idx >> 6, nl = idx & 63;
                int kg = kg0 + kk - IN_DIM;
                aS[kk][nl] = cosf(tS[nl] * omega[kg] + phase[kg]);
            }
        }
        __syncthreads();

        #pragma unroll
        for (int k = 0; k < KC; ++k) {
            const float4 av = *(const float4*)&aS[k][ty * 4];
            const float4 wv = *(const float4*)&wS[k][tx * 4];
            acc[0][0] = fmaf(av.x, wv.x, acc[0][0]);
            acc[0][1] = fmaf(av.x, wv.y, acc[0][1]);
            acc[0][2] = fmaf(av.x, wv.z, acc[0][2]);
            acc[0][3] = fmaf(av.x, wv.w, acc[0][3]);
            acc[1][0] = fmaf(av.y, wv.x, acc[1][0]);
            acc[1][1] = fmaf(av.y, wv.y, acc[1][1]);
            acc[1][2] = fmaf(av.y, wv.z, acc[1][2]);
            acc[1][3] = fmaf(av.y, wv.w, acc[1][3]);
            acc[2][0] = fmaf(av.z, wv.x, acc[2][0]);
            acc[2][1] = fmaf(av.z, wv.y, acc[2][1]);
            acc[2][2] = fmaf(av.z, wv.z, acc[2][2]);
            acc[2][3] = fmaf(av.z, wv.w, acc[2][3]);
            acc[3][0] = fmaf(av.w, wv.x, acc[3][0]);
            acc[3][1] = fmaf(av.w, wv.y, acc[3][1]);
            acc[3][2] = fmaf(av.w, wv.z, acc[3][2]);
            acc[3][3] = fmaf(av.w, wv.w, acc[3][3]);
        }
    }

    // epilogue: per-head scores (+ hw head-dot if FINAL; else bf16 h stores)
    const float4 as = ((const float4*)asrc)[tx];
    const float4 ad = ((const float4*)adst)[tx];
    float4 wh = make_float4(0.f, 0.f, 0.f, 0.f);
    if (FINAL) wh = ((const float4*)whead)[tx];
    #pragma unroll
    for (int j = 0; j < 4; ++j) {
        const int n = base + ty * 4 + j;
        if (!FINAL && n < N_NODES) {
            ushort4 o;
            o.x = f2bf(acc[j][0]); o.y = f2bf(acc[j][1]);
            o.z = f2bf(acc[j][2]); o.w = f2bf(acc[j][3]);
            *(ushort4*)(hfeat16 + (size_t)n * 64 + tx * 4) = o;
        }
        float vs = acc[j][0] * as.x + acc[j][1] * as.y
                 + acc[j][2] * as.z + acc[j][3] * as.w;
        float vd = acc[j][0] * ad.x + acc[j][1] * ad.y
                 + acc[j][2] * ad.z + acc[j][3] * ad.w;
        float vw = 0.f;
        if (FINAL)
            vw = acc[j][0] * wh.x + acc[j][1] * wh.y
               + acc[j][2] * wh.z + acc[j][3] * wh.w;
        vs += __shfl_xor(vs, 1, 64); vs += __shfl_xor(vs, 2, 64);
        vd += __shfl_xor(vd, 1, 64); vd += __shfl_xor(vd, 2, 64);
        if (FINAL) { vw += __shfl_xor(vw, 1, 64); vw += __shfl_xor(vw, 2, 64); }
        if ((tx & 3) == 0 && n < N_NODES) {
            if (FINAL) {
                const int hh = tx >> 2;
                l1tab[(size_t)n * 8 + hh * 2]     = vs * LOG2E;
                l1tab[(size_t)n * 8 + hh * 2 + 1] = vw;
                s_dst[n * 4 + hh] = vd * LOG2E;
            } else {
                s_src[n * 4 + (tx >> 2)] = vs * LOG2E;   // exp2 domain
                s_dst[n * 4 + (tx >> 2)] = vd * LOG2E;
            }
        }
    }
}

// ---------------- CSR build: count-matrix two-level bucket sort ----------
// Bucket = dst>>8 (196 buckets x 256 nodes). All random writes are confined
// to windows owned by a SINGLE block -> structural write merging.
// cmat[chunk][bucket] counts let bin run SINGLE-PASS with ZERO global
// atomics (base = cmat-prefix + bstart), replacing bhist+2-pass-bin.

// per-chunk bucket counts (LDS hist; dst read int4 non-temporal)
__global__ __launch_bounds__(256) void count_kernel(
    const int* __restrict__ dst, int* __restrict__ cmat)
{
    __shared__ int c[NBK];
    for (int t = threadIdx.x; t < NBK; t += 256) c[t] = 0;
    __syncthreads();
    const int b4 = blockIdx.x * (BIN_CHUNK / 4);
    const int e4n = N_EDGES / 4;       // E % 4 == 0
    const vint4* d4p = (const vint4*)dst;
    #pragma unroll
    for (int q = 0; q < BIN_CHUNK / 4 / 256; ++q) {
        int i4 = b4 + q * 256 + threadIdx.x;
        if (i4 < e4n) {
            vint4 d4 = __builtin_nontemporal_load(d4p + i4);
            atomicAdd(&c[d4.x >> 8], 1);
            atomicAdd(&c[d4.y >> 8], 1);
            atomicAdd(&c[d4.z >> 8], 1);
            atomicAdd(&c[d4.w >> 8], 1);
        }
    }
    __syncthreads();
    for (int t = threadIdx.x; t < NBK; t += 256)
        cmat[blockIdx.x * NBK + t] = c[t];
}

// in-place column-scan of cmat (-> per-chunk exclusive base within bucket)
// + bucket-total exclusive scan -> bstart[0..NBK]
__global__ __launch_bounds__(256) void cscan_kernel(
    int* __restrict__ cmat, int* __restrict__ bstart)
{
    __shared__ int s[256];
    const int t = threadIdx.x;
    int run = 0;
    if (t < NBK) {
        #pragma unroll 8
        for (int c = 0; c < BIN_GRID; ++c) {
            int v = cmat[c * NBK + t];
            cmat[c * NBK + t] = run;
            run += v;
        }
    }
    s[t] = (t < NBK) ? run : 0;
    const int own = s[t];
    __syncthreads();
    #pragma unroll
    for (int off = 1; off < 256; off <<= 1) {
        int u = (t >= off) ? s[t - off] : 0;
        __syncthreads();
        s[t] += u;
        __syncthreads();
    }
    if (t < NBK) bstart[t] = s[t] - own;
    if (t == NBK - 1) bstart[NBK] = s[t];
}

// single-pass bin: no global atomics; per-chunk bases precomputed.
// all streaming reads non-temporal (keep run-tail lines L2-resident).
__global__ __launch_bounds__(256) void bin_kernel(
    const int* __restrict__ dst, const int* __restrict__ src,
    const float* __restrict__ ew,
    const int* __restrict__ cmat, const int* __restrict__ bstart,
    int* __restrict__ rdst, int2* __restrict__ rpair)
{
    __shared__ int gb[NBK];
    __shared__ int cnt[NBK];
    const int tid = threadIdx.x;
    for (int t = tid; t < NBK; t += 256) {
        gb[t] = cmat[blockIdx.x * NBK + t] + bstart[t];
        cnt[t] = 0;
    }
    __syncthreads();

    const int b4 = blockIdx.x * (BIN_CHUNK / 4);
    const int e4n = N_EDGES / 4;       // E % 4 == 0
    const vint4* d4p = (const vint4*)dst;
    const vint4* s4p = (const vint4*)src;
    const vfloat4* w4p = (const vfloat4*)ew;

    #pragma unroll
    for (int q = 0; q < BIN_CHUNK / 4 / 256; ++q) {
        int i4 = b4 + q * 256 + tid;
        if (i4 < e4n) {
            vint4 d4 = __builtin_nontemporal_load(d4p + i4);
            vint4 s4 = __builtin_nontemporal_load(s4p + i4);
            vfloat4 w4 = __builtin_nontemporal_load(w4p + i4);
            #pragma unroll
            for (int j = 0; j < 4; ++j) {
                const int d = j == 0 ? d4.x : j == 1 ? d4.y : j == 2 ? d4.z : d4.w;
                const int s = j == 0 ? s4.x : j == 1 ? s4.y : j == 2 ? s4.z : s4.w;
                const float w = j == 0 ? w4.x : j == 1 ? w4.y : j == 2 ? w4.z : w4.w;
                const int bk = d >> 8;
                const int r = atomicAdd(&cnt[bk], 1);
                const int pos = gb[bk] + r;
                rdst[pos] = d;
                rpair[pos] = make_int2(s, __float_as_int(w));
            }
        }
    }
}

// one block per bucket: build deg/rowptr locally (LDS hist+scan) then place
// epair via LDS cursors. rpair read once -> non-temporal; rdst read twice.
__global__ __launch_bounds__(256) void place_kernel(
    const int* __restrict__ bstart, const int* __restrict__ rdst,
    const int2* __restrict__ rpair,
    int* __restrict__ deg, int* __restrict__ rowptr, int2* __restrict__ epair)
{
    __shared__ int ldeg[256];
    __shared__ int ls[256];
    __shared__ int lcur[256];
    const int t = threadIdx.x;
    const int b = blockIdx.x;
    const int lo = bstart[b], hi = bstart[b + 1];
    const int nbase = b << 8;

    ldeg[t] = 0;
    __syncthreads();
    for (int i = lo + t; i < hi; i += 256)
        atomicAdd(&ldeg[rdst[i] & 255], 1);
    __syncthreads();

    const int v = ldeg[t];
    ls[t] = v;
    __syncthreads();
    #pragma unroll
    for (int off = 1; off < 256; off <<= 1) {
        int u = (t >= off) ? ls[t - off] : 0;
        __syncthreads();
        ls[t] += u;
        __syncthreads();
    }
    const int excl = ls[t] - v + lo;
    const int n = nbase + t;
    if (n < N_NODES) { rowptr[n] = excl; deg[n] = v; }
    lcur[t] = excl;
    __syncthreads();

    const vint2* rpv = (const vint2*)rpair;
    for (int i = lo + t; i < hi; i += 256) {
        const int d = rdst[i];
        vint2 rp = __builtin_nontemporal_load(rpv + i);
        const int pos = atomicAdd(&lcur[d & 255], 1);
        epair[pos] = make_int2(rp.x, rp.y);
    }
}

// ---------------- layer-0 aggregation (full 64-dim output) ----------------
// one wave per node; 8 subgroups x 8 lanes, 8 edges in flight; each lane
// holds 8 bf16 features (ONE uint4 = 16B load, unpacked in-register).
// epair read non-temporally. no max-subtraction; exp2 domain.
__global__ __launch_bounds__(256) void aggregate_kernel(
    const int* __restrict__ rowptr, const int* __restrict__ deg,
    const int2* __restrict__ epair,
    const float* __restrict__ s_src, const float* __restrict__ s_dst,
    const unsigned short* __restrict__ hfeat16,
    float* __restrict__ outp)
{
    const int n = blockIdx.x * 4 + (threadIdx.x >> 6);
    if (n >= N_NODES) return;
    const int lane = threadIdx.x & 63;
    const int g = lane >> 3;          // subgroup (edge slot 0..7)
    const int sl = lane & 7;          // feature octet
    const int hh = sl >> 1;           // head of my features
    const float sdst = s_dst[n * 4 + hh];
    const int beg = rowptr[n];
    const int cnt = deg[n];
    const vint2* epv = (const vint2*)epair + beg;
    const vint2 zz = {0, 0};

    float den = 0.f;
    float4 a0 = make_float4(0.f, 0.f, 0.f, 0.f);
    float4 a1 = make_float4(0.f, 0.f, 0.f, 0.f);

    int i = g;
    vint2 ep = (i < cnt) ? __builtin_nontemporal_load(epv + i) : zz;
    while (i < cnt) {
        const int inext = i + 8;
        vint2 epn = (inext < cnt) ? __builtin_nontemporal_load(epv + inext) : zz;
        const int s = ep.x;
        const float w = __int_as_float(ep.y);
        float sc = s_src[(size_t)s * 4 + hh] + sdst;
        sc = fmaxf(sc, 0.2f * sc);                       // leaky relu (log2 domain)
        const float p = __builtin_amdgcn_exp2f(sc) * w;
        const uint4 hv = *(const uint4*)(hfeat16 + (size_t)s * 64 + sl * 8);
        den += p;
        a0.x = fmaf(p, bf_lo(hv.x), a0.x); a0.y = fmaf(p, bf_hi(hv.x), a0.y);
        a0.z = fmaf(p, bf_lo(hv.y), a0.z); a0.w = fmaf(p, bf_hi(hv.y), a0.w);
        a1.x = fmaf(p, bf_lo(hv.z), a1.x); a1.y = fmaf(p, bf_hi(hv.z), a1.y);
        a1.z = fmaf(p, bf_lo(hv.w), a1.z); a1.w = fmaf(p, bf_hi(hv.w), a1.w);
        ep = epn; i = inext;
    }

    // merge 8 subgroups (lane bits 3,4,5)
    #pragma unroll
    for (int off = 8; off <= 32; off <<= 1) {
        den  += __shfl_xor(den, off, 64);
        a0.x += __shfl_xor(a0.x, off, 64); a0.y += __shfl_xor(a0.y, off, 64);
        a0.z += __shfl_xor(a0.z, off, 64); a0.w += __shfl_xor(a0.w, off, 64);
        a1.x += __shfl_xor(a1.x, off, 64); a1.y += __shfl_xor(a1.y, off, 64);
        a1.z += __shfl_xor(a1.z, off, 64); a1.w += __shfl_xor(a1.w, off, 64);
    }

    const float inv = 1.f / (den + 1e-16f);
    if (g == 0) {
        float4 v0, v1;
        v0.x = a0.x * inv; v0.x = v0.x > 0.f ? v0.x : expm1f(v0.x);
        v0.y = a0.y * inv; v0.y = v0.y > 0.f ? v0.y : expm1f(v0.y);
        v0.z = a0.z * inv; v0.z = v0.z > 0.f ? v0.z : expm1f(v0.z);
        v0.w = a0.w * inv; v0.w = v0.w > 0.f ? v0.w : expm1f(v0.w);
        v1.x = a1.x * inv; v1.x = v1.x > 0.f ? v1.x : expm1f(v1.x);
        v1.y = a1.y * inv; v1.y = v1.y > 0.f ? v1.y : expm1f(v1.y);
        v1.z = a1.z * inv; v1.z = v1.z > 0.f ? v1.z : expm1f(v1.z);
        v1.w = a1.w * inv; v1.w = v1.w > 0.f ? v1.w : expm1f(v1.w);
        float4* op = (float4*)(outp + (size_t)n * 64 + sl * 8);
        op[0] = v0; op[1] = v1;
    }
}

// ---------------- layer-1 head-collapsed aggregation ----------------
// out[n] = sum_h (sum_e p_eh * hw[s_e,h]) / den_h + b. Per edge only one
// float2 {s,hw} is gathered from the interleaved 32B l1tab record.
// one wave per node; 16 subgroups x 4 lanes; lane = (edge slot g, head h).
__global__ __launch_bounds__(256) void head_aggregate_kernel(
    const int* __restrict__ rowptr, const int* __restrict__ deg,
    const int2* __restrict__ epair,
    const float* __restrict__ l1tab, const float* __restrict__ s_dst,
    const float* __restrict__ bhead, float* __restrict__ outp)
{
    const int n = blockIdx.x * 4 + (threadIdx.x >> 6);
    if (n >= N_NODES) return;
    const int lane = threadIdx.x & 63;
    const int g = lane >> 2;          // subgroup (edge slot 0..15)
    const int h = lane & 3;           // head
    const float sdst = s_dst[n * 4 + h];
    const int beg = rowptr[n];
    const int cnt = deg[n];
    const vint2* epv = (const vint2*)epair + beg;
    const vint2 zz = {0, 0};

    float den = 0.f, num = 0.f;

    int i = g;
    vint2 ep = (i < cnt) ? __builtin_nontemporal_load(epv + i) : zz;
    while (i < cnt) {
        const int inext = i + 16;
        vint2 epn = (inext < cnt) ? __builtin_nontemporal_load(epv + inext) : zz;
        const int s = ep.x;
        const float w = __int_as_float(ep.y);
        const float2 rec = *(const float2*)(l1tab + (size_t)s * 8 + h * 2);
        float sc = rec.x + sdst;
        sc = fmaxf(sc, 0.2f * sc);                       // leaky relu (log2 domain)
        const float p = __builtin_amdgcn_exp2f(sc) * w;
        den += p;
        num = fmaf(p, rec.y, num);
        ep = epn; i = inext;
    }

    // merge 16 subgroups (lane bits 2..5)
    #pragma unroll
    for (int off = 4; off <= 32; off <<= 1) {
        den += __shfl_xor(den, off, 64);
        num += __shfl_xor(num, off, 64);
    }

    float v = num / (den + 1e-16f);
    v += __shfl_xor(v, 1, 64);
    v += __shfl_xor(v, 2, 64);
    if (lane == 0) outp[n] = v + bhead[0];
}

extern "C" void kernel_launch(void* const* d_in, const int* in_sizes, int n_in,
                              void* d_out, int out_size, void* d_ws, size_t ws_size,
                              hipStream_t stream) {
    const float* x      = (const float*)d_in[0];
    const int*   eidx   = (const int*)d_in[1];
    const float* ew     = (const float*)d_in[2];
    const float* tim    = (const float*)d_in[3];
    const float* omega0 = (const float*)d_in[4];
    const float* phase0 = (const float*)d_in[5];
    const float* W0     = (const float*)d_in[6];
    const float* asrc0  = (const float*)d_in[7];
    const float* adst0  = (const float*)d_in[8];
    const float* omega1 = (const float*)d_in[9];
    const float* phase1 = (const float*)d_in[10];
    const float* W1     = (const float*)d_in[11];
    const float* asrc1  = (const float*)d_in[12];
    const float* adst1  = (const float*)d_in[13];
    const float* Whead  = (const float*)d_in[14];
    const float* bhead  = (const float*)d_in[15];
    float* out = (float*)d_out;

    const int* src = eidx;
    const int* dst = eidx + N_EDGES;

    float* ws = (float*)d_ws;
    unsigned short* hfeat16 = (unsigned short*)ws;   // N*64 ushorts (6.4MB)
    float* x1    = (float*)(hfeat16 + (size_t)N_NODES * 64);  // N*64 floats
    float* s_src = x1    + (size_t)N_NODES * 64;     // N*4
    float* s_dst = s_src + (size_t)N_NODES * 4;      // N*4
    int2* epair  = (int2*)(s_dst + (size_t)N_NODES * 4);   // E int2
    int* deg     = (int*)(epair + (size_t)N_EDGES);  // N
    int* rowptr  = deg + N_NODES;                    // N
    int* bstart  = rowptr + N_NODES;                 // NBK+1
    int* cmat    = bstart + NBK + 1;                 // BIN_GRID*NBK (153KB)
    float* l1tab = (float*)(cmat + BIN_GRID * NBK);  // N*8 floats (1.6MB)
    // record arrays alias dead buffers: consumed by place() before their
    // aliases are written (hfeat16 by transform<128>, x1 by aggregate).
    int*  rdst  = (int*)hfeat16;                     // E ints
    int2* rpair = (int2*)x1;                         // E int2

    const int tf_grid  = (N_NODES + 63) / 64;        // 782
    const int agg_grid = (N_NODES + 3) / 4;

    // ---- CSR build (count-matrix bucket sort; shared by both layers) ----
    count_kernel<<<BIN_GRID, 256, 0, stream>>>(dst, cmat);
    cscan_kernel<<<1, 256, 0, stream>>>(cmat, bstart);
    bin_kernel<<<BIN_GRID, 256, 0, stream>>>(dst, src, ew, cmat, bstart, rdst, rpair);
    place_kernel<<<NBK, 256, 0, stream>>>(bstart, rdst, rpair, deg, rowptr, epair);

    // ---- layer 0 ----
    transform_kernel<128, 0><<<tf_grid, 256, 0, stream>>>(
        x, tim, omega0, phase0, W0, asrc0, adst0, Whead,
        hfeat16, s_src, s_dst, l1tab);
    aggregate_kernel<<<agg_grid, 256, 0, stream>>>(
        rowptr, deg, epair, s_src, s_dst, hfeat16, x1);

    // ---- layer 1 (head-collapsed: h@Whead folded into per-node hw) ----
    transform_kernel<64, 1><<<tf_grid, 256, 0, stream>>>(
        x1, tim, omega1, phase1, W1, asrc1, adst1, Whead,
        hfeat16, s_src, s_dst, l1tab);
    head_aggregate_kernel<<<agg_grid, 256, 0, stream>>>(
        rowptr, deg, epair, l1tab, s_dst, bhead, out);
}

// Round 19
// 200.952 us; speedup vs baseline: 1.3919x; 1.0404x over previous
//
#include <hip/hip_runtime.h>
#include <hip/hip_bf16.h>
#include <math.h>

#define N_NODES 50000
#define N_EDGES 1600000
#define TE 64
#define LOG2E 1.44269504088896340736f
#define NBK 196            // dst buckets: bucket = dst >> 8 (256 nodes each)
#define BIN_CHUNK 8192
#define BIN_GRID ((N_EDGES + BIN_CHUNK - 1) / BIN_CHUNK)   // 196

typedef int vint2 __attribute__((ext_vector_type(2)));
typedef int vint4 __attribute__((ext_vector_type(4)));
typedef float vfloat4 __attribute__((ext_vector_type(4)));
typedef unsigned int uint;

__device__ __forceinline__ unsigned short f2bf(float f) {
    uint u = __float_as_uint(f);
    return (unsigned short)((u + 0x7fffu + ((u >> 16) & 1u)) >> 16);   // RNE
}
__device__ __forceinline__ float bf_lo(uint u) { return __uint_as_float(u << 16); }
__device__ __forceinline__ float bf_hi(uint u) { return __uint_as_float(u & 0xffff0000u); }

// ---------------- node transform ----------------
// h = concat(x, cos(t*omega+phase)) @ W. FINAL=0: h stored bf16 + s_src/s_dst.
// FINAL=1: only the head-projected scalar hw[n,h] and s_src are needed
// downstream (head projection commutes with the alpha-weighted edge sum);
// writes interleaved l1tab[n] = {s0,hw0,s1,hw1,...} (32B record) + s_dst.
template<int IN_DIM, int FINAL>
__global__ __launch_bounds__(256) void transform_kernel(
    const float* __restrict__ xin, const float* __restrict__ tim,
    const float* __restrict__ omega, const float* __restrict__ phase,
    const float* __restrict__ W, const float* __restrict__ asrc,
    const float* __restrict__ adst, const float* __restrict__ whead,
    unsigned short* __restrict__ hfeat16,
    float* __restrict__ s_src, float* __restrict__ s_dst,
    float* __restrict__ l1tab)
{
    constexpr int K = IN_DIM + TE;
    constexpr int KC = 32;             // k-chunk
    constexpr int NCH = K / KC;
    constexpr int BN = 64;             // nodes per block
    __shared__ float aS[KC][68];       // transposed a-chunk (padded row: 272B)
    __shared__ float wS[KC][64];
    __shared__ float tS[BN];

    const int tid = threadIdx.x;
    const int base = blockIdx.x * BN;

    if (tid < BN) {
        int n = base + tid;
        tS[tid] = (n < N_NODES) ? tim[n] : 0.f;
    }

    const int ty = tid >> 4;           // node quad: nodes ty*4 .. ty*4+3
    const int tx = tid & 15;           // col slot: cols tx*4 .. tx*4+3

    float acc[4][4] = {};

    for (int ch = 0; ch < NCH; ++ch) {
        const int kg0 = ch * KC;
        __syncthreads();               // previous chunk fully consumed

        // stage W chunk: 32x64 floats = 512 float4, 2 per thread (coalesced)
        #pragma unroll
        for (int j = 0; j < 2; ++j) {
            int idx = tid + j * 256;                    // float4 index
            int kk = idx >> 4, c4 = idx & 15;
            *(float4*)&wS[kk][c4 * 4] =
                ((const float4*)(W + (size_t)(kg0 + kk) * 64))[c4];
        }

        // stage a chunk (transposed)
        if (kg0 < IN_DIM) {
            #pragma unroll
            for (int j = 0; j < 2; ++j) {
                int idx = tid + j * 256;
                int nl = idx >> 3, kk = (idx & 7) * 4;
                int n = base + nl;
                float4 v = (n < N_NODES)
                    ? ((const float4*)(xin + (size_t)n * IN_DIM + kg0))[idx & 7]
                    : make_float4(0.f, 0.f, 0.f, 0.f);
                aS[kk + 0][nl] = v.x;
                aS[kk + 1][nl] = v.y;
                aS[kk + 2][nl] = v.z;
                aS[kk + 3][nl] = v.w;
            }
        } else {
            #pragma unroll
            for (int j = 0; j < 8; ++j) {
                int idx = tid + j * 256;
                int kk = idx >> 6, nl = idx & 63;
                int kg = kg0 + kk - IN_DIM;
                aS[kk][nl] = cosf(tS[nl] * omega[kg] + phase[kg]);
            }
        }
        __syncthreads();

        #pragma unroll
        for (int k = 0; k < KC; ++k) {
            const float4 av = *(const float4*)&aS[k][ty * 4];
            const float4 wv = *(const float4*)&wS[k][tx * 4];
            acc[0][0] = fmaf(av.x, wv.x, acc[0][0]);
            acc[0][1] = fmaf(av.x, wv.y, acc[0][1]);
            acc[0][2] = fmaf(av.x, wv.z, acc[0][2]);
            acc[0][3] = fmaf(av.x, wv.w, acc[0][3]);
            acc[1][0] = fmaf(av.y, wv.x, acc[1][0]);
            acc[1][1] = fmaf(av.y, wv.y, acc[1][1]);
            acc[1][2] = fmaf(av.y, wv.z, acc[1][2]);
            acc[1][3] = fmaf(av.y, wv.w, acc[1][3]);
            acc[2][0] = fmaf(av.z, wv.x, acc[2][0]);
            acc[2][1] = fmaf(av.z, wv.y, acc[2][1]);
            acc[2][2] = fmaf(av.z, wv.z, acc[2][2]);
            acc[2][3] = fmaf(av.z, wv.w, acc[2][3]);
            acc[3][0] = fmaf(av.w, wv.x, acc[3][0]);
            acc[3][1] = fmaf(av.w, wv.y, acc[3][1]);
            acc[3][2] = fmaf(av.w, wv.z, acc[3][2]);
            acc[3][3] = fmaf(av.w, wv.w, acc[3][3]);
        }
    }

    // epilogue: per-head scores (+ hw head-dot if FINAL; else bf16 h stores)
    const float4 as = ((const float4*)asrc)[tx];
    const float4 ad = ((const float4*)adst)[tx];
    float4 wh = make_float4(0.f, 0.f, 0.f, 0.f);
    if (FINAL) wh = ((const float4*)whead)[tx];
    #pragma unroll
    for (int j = 0; j < 4; ++j) {
        const int n = base + ty * 4 + j;
        if (!FINAL && n < N_NODES) {
            ushort4 o;
            o.x = f2bf(acc[j][0]); o.y = f2bf(acc[j][1]);
            o.z = f2bf(acc[j][2]); o.w = f2bf(acc[j][3]);
            *(ushort4*)(hfeat16 + (size_t)n * 64 + tx * 4) = o;
        }
        float vs = acc[j][0] * as.x + acc[j][1] * as.y
                 + acc[j][2] * as.z + acc[j][3] * as.w;
        float vd = acc[j][0] * ad.x + acc[j][1] * ad.y
                 + acc[j][2] * ad.z + acc[j][3] * ad.w;
        float vw = 0.f;
        if (FINAL)
            vw = acc[j][0] * wh.x + acc[j][1] * wh.y
               + acc[j][2] * wh.z + acc[j][3] * wh.w;
        vs += __shfl_xor(vs, 1, 64); vs += __shfl_xor(vs, 2, 64);
        vd += __shfl_xor(vd, 1, 64); vd += __shfl_xor(vd, 2, 64);
        if (FINAL) { vw += __shfl_xor(vw, 1, 64); vw += __shfl_xor(vw, 2, 64); }
        if ((tx & 3) == 0 && n < N_NODES) {
            if (FINAL) {
                const int hh = tx >> 2;
                l1tab[(size_t)n * 8 + hh * 2]     = vs * LOG2E;
                l1tab[(size_t)n * 8 + hh * 2 + 1] = vw;
                s_dst[n * 4 + hh] = vd * LOG2E;
            } else {
                s_src[n * 4 + (tx >> 2)] = vs * LOG2E;   // exp2 domain
                s_dst[n * 4 + (tx >> 2)] = vd * LOG2E;
            }
        }
    }
}

// ---------------- CSR build: count-matrix two-level bucket sort ----------
// Bucket = dst>>8 (196 buckets x 256 nodes). All random writes are confined
// to windows owned by a SINGLE block -> structural write merging.
// cmat[chunk][bucket] counts let bin run SINGLE-PASS with ZERO global
// atomics (base = cmat-prefix + bstart).

// per-chunk bucket counts (LDS hist; dst read int4 non-temporal)
__global__ __launch_bounds__(256) void count_kernel(
    const int* __restrict__ dst, int* __restrict__ cmat)
{
    __shared__ int c[NBK];
    for (int t = threadIdx.x; t < NBK; t += 256) c[t] = 0;
    __syncthreads();
    const int b4 = blockIdx.x * (BIN_CHUNK / 4);
    const int e4n = N_EDGES / 4;       // E % 4 == 0
    const vint4* d4p = (const vint4*)dst;
    #pragma unroll
    for (int q = 0; q < BIN_CHUNK / 4 / 256; ++q) {
        int i4 = b4 + q * 256 + threadIdx.x;
        if (i4 < e4n) {
            vint4 d4 = __builtin_nontemporal_load(d4p + i4);
            atomicAdd(&c[d4.x >> 8], 1);
            atomicAdd(&c[d4.y >> 8], 1);
            atomicAdd(&c[d4.z >> 8], 1);
            atomicAdd(&c[d4.w >> 8], 1);
        }
    }
    __syncthreads();
    for (int t = threadIdx.x; t < NBK; t += 256)
        cmat[blockIdx.x * NBK + t] = c[t];
}

// in-place column-scan of cmat (-> per-chunk exclusive base within bucket)
// + bucket-total exclusive scan -> bstart[0..NBK]
__global__ __launch_bounds__(256) void cscan_kernel(
    int* __restrict__ cmat, int* __restrict__ bstart)
{
    __shared__ int s[256];
    const int t = threadIdx.x;
    int run = 0;
    if (t < NBK) {
        #pragma unroll 8
        for (int c = 0; c < BIN_GRID; ++c) {
            int v = cmat[c * NBK + t];
            cmat[c * NBK + t] = run;
            run += v;
        }
    }
    s[t] = (t < NBK) ? run : 0;
    const int own = s[t];
    __syncthreads();
    #pragma unroll
    for (int off = 1; off < 256; off <<= 1) {
        int u = (t >= off) ? s[t - off] : 0;
        __syncthreads();
        s[t] += u;
        __syncthreads();
    }
    if (t < NBK) bstart[t] = s[t] - own;
    if (t == NBK - 1) bstart[NBK] = s[t];
}

// single-pass bin: no global atomics; per-chunk bases precomputed.
// all streaming reads non-temporal (keep run-tail lines L2-resident).
__global__ __launch_bounds__(256) void bin_kernel(
    const int* __restrict__ dst, const int* __restrict__ src,
    const float* __restrict__ ew,
    const int* __restrict__ cmat, const int* __restrict__ bstart,
    int* __restrict__ rdst, int2* __restrict__ rpair)
{
    __shared__ int gb[NBK];
    __shared__ int cnt[NBK];
    const int tid = threadIdx.x;
    for (int t = tid; t < NBK; t += 256) {
        gb[t] = cmat[blockIdx.x * NBK + t] + bstart[t];
        cnt[t] = 0;
    }
    __syncthreads();

    const int b4 = blockIdx.x * (BIN_CHUNK / 4);
    const int e4n = N_EDGES / 4;       // E % 4 == 0
    const vint4* d4p = (const vint4*)dst;
    const vint4* s4p = (const vint4*)src;
    const vfloat4* w4p = (const vfloat4*)ew;

    #pragma unroll
    for (int q = 0; q < BIN_CHUNK / 4 / 256; ++q) {
        int i4 = b4 + q * 256 + tid;
        if (i4 < e4n) {
            vint4 d4 = __builtin_nontemporal_load(d4p + i4);
            vint4 s4 = __builtin_nontemporal_load(s4p + i4);
            vfloat4 w4 = __builtin_nontemporal_load(w4p + i4);
            #pragma unroll
            for (int j = 0; j < 4; ++j) {
                const int d = j == 0 ? d4.x : j == 1 ? d4.y : j == 2 ? d4.z : d4.w;
                const int s = j == 0 ? s4.x : j == 1 ? s4.y : j == 2 ? s4.z : s4.w;
                const float w = j == 0 ? w4.x : j == 1 ? w4.y : j == 2 ? w4.z : w4.w;
                const int bk = d >> 8;
                const int r = atomicAdd(&cnt[bk], 1);
                const int pos = gb[bk] + r;
                rdst[pos] = d;
                rpair[pos] = make_int2(s, __float_as_int(w));
            }
        }
    }
}

// one block per bucket: build deg/rowptr locally (LDS hist+scan) then place
// epair via LDS cursors. rpair read once -> non-temporal; rdst read twice.
__global__ __launch_bounds__(256) void place_kernel(
    const int* __restrict__ bstart, const int* __restrict__ rdst,
    const int2* __restrict__ rpair,
    int* __restrict__ deg, int* __restrict__ rowptr, int2* __restrict__ epair)
{
    __shared__ int ldeg[256];
    __shared__ int ls[256];
    __shared__ int lcur[256];
    const int t = threadIdx.x;
    const int b = blockIdx.x;
    const int lo = bstart[b], hi = bstart[b + 1];
    const int nbase = b << 8;

    ldeg[t] = 0;
    __syncthreads();
    for (int i = lo + t; i < hi; i += 256)
        atomicAdd(&ldeg[rdst[i] & 255], 1);
    __syncthreads();

    const int v = ldeg[t];
    ls[t] = v;
    __syncthreads();
    #pragma unroll
    for (int off = 1; off < 256; off <<= 1) {
        int u = (t >= off) ? ls[t - off] : 0;
        __syncthreads();
        ls[t] += u;
        __syncthreads();
    }
    const int excl = ls[t] - v + lo;
    const int n = nbase + t;
    if (n < N_NODES) { rowptr[n] = excl; deg[n] = v; }
    lcur[t] = excl;
    __syncthreads();

    const vint2* rpv = (const vint2*)rpair;
    for (int i = lo + t; i < hi; i += 256) {
        const int d = rdst[i];
        vint2 rp = __builtin_nontemporal_load(rpv + i);
        const int pos = atomicAdd(&lcur[d & 255], 1);
        epair[pos] = make_int2(rp.x, rp.y);
    }
}

// ---------------- layer-0 aggregation (full 64-dim output) ----------------
// one wave per node; 8 subgroups x 8 lanes; UNROLL-BY-2: each iteration
// processes edges i and i+8 with both 16B hfeat loads + s_src loads + next
// epairs issued before any FMA -> 2x memory-level parallelism (bf16 halved
// bytes-in-flight made the kernel latency-bound; this restores concurrency).
// w=0 zero-fill keeps the tail guard-free. epair read non-temporally.
__global__ __launch_bounds__(256) void aggregate_kernel(
    const int* __restrict__ rowptr, const int* __restrict__ deg,
    const int2* __restrict__ epair,
    const float* __restrict__ s_src, const float* __restrict__ s_dst,
    const unsigned short* __restrict__ hfeat16,
    float* __restrict__ outp)
{
    const int n = blockIdx.x * 4 + (threadIdx.x >> 6);
    if (n >= N_NODES) return;
    const int lane = threadIdx.x & 63;
    const int g = lane >> 3;          // subgroup (edge slot 0..7)
    const int sl = lane & 7;          // feature octet
    const int hh = sl >> 1;           // head of my features
    const float sdst = s_dst[n * 4 + hh];
    const int beg = rowptr[n];
    const int cnt = deg[n];
    const vint2* epv = (const vint2*)epair + beg;
    const vint2 zz = {0, 0};

    float den = 0.f;
    float4 a0 = make_float4(0.f, 0.f, 0.f, 0.f);
    float4 a1 = make_float4(0.f, 0.f, 0.f, 0.f);

    int i = g;
    vint2 ep0 = (i < cnt) ? __builtin_nontemporal_load(epv + i) : zz;
    vint2 ep1 = (i + 8 < cnt) ? __builtin_nontemporal_load(epv + i + 8) : zz;
    while (i < cnt) {
        const int s0 = ep0.x, s1 = ep1.x;
        const float w0 = __int_as_float(ep0.y);
        const float w1 = __int_as_float(ep1.y);
        const float ss0 = s_src[(size_t)s0 * 4 + hh];
        const float ss1 = s_src[(size_t)s1 * 4 + hh];
        const uint4 hv0 = *(const uint4*)(hfeat16 + (size_t)s0 * 64 + sl * 8);
        const uint4 hv1 = *(const uint4*)(hfeat16 + (size_t)s1 * 64 + sl * 8);
        vint2 en0 = (i + 16 < cnt) ? __builtin_nontemporal_load(epv + i + 16) : zz;
        vint2 en1 = (i + 24 < cnt) ? __builtin_nontemporal_load(epv + i + 24) : zz;

        float sc0 = ss0 + sdst;
        sc0 = fmaxf(sc0, 0.2f * sc0);                    // leaky relu (log2 domain)
        const float p0 = __builtin_amdgcn_exp2f(sc0) * w0;
        float sc1 = ss1 + sdst;
        sc1 = fmaxf(sc1, 0.2f * sc1);
        const float p1 = __builtin_amdgcn_exp2f(sc1) * w1;
        den += p0 + p1;
        a0.x = fmaf(p0, bf_lo(hv0.x), a0.x); a0.y = fmaf(p0, bf_hi(hv0.x), a0.y);
        a0.z = fmaf(p0, bf_lo(hv0.y), a0.z); a0.w = fmaf(p0, bf_hi(hv0.y), a0.w);
        a1.x = fmaf(p0, bf_lo(hv0.z), a1.x); a1.y = fmaf(p0, bf_hi(hv0.z), a1.y);
        a1.z = fmaf(p0, bf_lo(hv0.w), a1.z); a1.w = fmaf(p0, bf_hi(hv0.w), a1.w);
        a0.x = fmaf(p1, bf_lo(hv1.x), a0.x); a0.y = fmaf(p1, bf_hi(hv1.x), a0.y);
        a0.z = fmaf(p1, bf_lo(hv1.y), a0.z); a0.w = fmaf(p1, bf_hi(hv1.y), a0.w);
        a1.x = fmaf(p1, bf_lo(hv1.z), a1.x); a1.y = fmaf(p1, bf_hi(hv1.z), a1.y);
        a1.z = fmaf(p1, bf_lo(hv1.w), a1.z); a1.w = fmaf(p1, bf_hi(hv1.w), a1.w);

        ep0 = en0; ep1 = en1; i += 16;
    }

    // merge 8 subgroups (lane bits 3,4,5)
    #pragma unroll
    for (int off = 8; off <= 32; off <<= 1) {
        den  += __shfl_xor(den, off, 64);
        a0.x += __shfl_xor(a0.x, off, 64); a0.y += __shfl_xor(a0.y, off, 64);
        a0.z += __shfl_xor(a0.z, off, 64); a0.w += __shfl_xor(a0.w, off, 64);
        a1.x += __shfl_xor(a1.x, off, 64); a1.y += __shfl_xor(a1.y, off, 64);
        a1.z += __shfl_xor(a1.z, off, 64); a1.w += __shfl_xor(a1.w, off, 64);
    }

    const float inv = 1.f / (den + 1e-16f);
    if (g == 0) {
        float4 v0, v1;
        v0.x = a0.x * inv; v0.x = v0.x > 0.f ? v0.x : expm1f(v0.x);
        v0.y = a0.y * inv; v0.y = v0.y > 0.f ? v0.y : expm1f(v0.y);
        v0.z = a0.z * inv; v0.z = v0.z > 0.f ? v0.z : expm1f(v0.z);
        v0.w = a0.w * inv; v0.w = v0.w > 0.f ? v0.w : expm1f(v0.w);
        v1.x = a1.x * inv; v1.x = v1.x > 0.f ? v1.x : expm1f(v1.x);
        v1.y = a1.y * inv; v1.y = v1.y > 0.f ? v1.y : expm1f(v1.y);
        v1.z = a1.z * inv; v1.z = v1.z > 0.f ? v1.z : expm1f(v1.z);
        v1.w = a1.w * inv; v1.w = v1.w > 0.f ? v1.w : expm1f(v1.w);
        float4* op = (float4*)(outp + (size_t)n * 64 + sl * 8);
        op[0] = v0; op[1] = v1;
    }
}

// ---------------- layer-1 head-collapsed aggregation ----------------
// out[n] = sum_h (sum_e p_eh * hw[s_e,h]) / den_h + b. Per edge only one
// float2 {s,hw} is gathered from the interleaved 32B l1tab record.
// one wave per node; 16 subgroups x 4 lanes; unroll-by-2 (edges i, i+16).
__global__ __launch_bounds__(256) void head_aggregate_kernel(
    const int* __restrict__ rowptr, const int* __restrict__ deg,
    const int2* __restrict__ epair,
    const float* __restrict__ l1tab, const float* __restrict__ s_dst,
    const float* __restrict__ bhead, float* __restrict__ outp)
{
    const int n = blockIdx.x * 4 + (threadIdx.x >> 6);
    if (n >= N_NODES) return;
    const int lane = threadIdx.x & 63;
    const int g = lane >> 2;          // subgroup (edge slot 0..15)
    const int h = lane & 3;           // head
    const float sdst = s_dst[n * 4 + h];
    const int beg = rowptr[n];
    const int cnt = deg[n];
    const vint2* epv = (const vint2*)epair + beg;
    const vint2 zz = {0, 0};

    float den = 0.f, num = 0.f;

    int i = g;
    vint2 ep0 = (i < cnt) ? __builtin_nontemporal_load(epv + i) : zz;
    vint2 ep1 = (i + 16 < cnt) ? __builtin_nontemporal_load(epv + i + 16) : zz;
    while (i < cnt) {
        const int s0 = ep0.x, s1 = ep1.x;
        const float w0 = __int_as_float(ep0.y);
        const float w1 = __int_as_float(ep1.y);
        const float2 rec0 = *(const float2*)(l1tab + (size_t)s0 * 8 + h * 2);
        const float2 rec1 = *(const float2*)(l1tab + (size_t)s1 * 8 + h * 2);
        vint2 en0 = (i + 32 < cnt) ? __builtin_nontemporal_load(epv + i + 32) : zz;
        vint2 en1 = (i + 48 < cnt) ? __builtin_nontemporal_load(epv + i + 48) : zz;

        float sc0 = rec0.x + sdst;
        sc0 = fmaxf(sc0, 0.2f * sc0);                    // leaky relu (log2 domain)
        const float p0 = __builtin_amdgcn_exp2f(sc0) * w0;
        float sc1 = rec1.x + sdst;
        sc1 = fmaxf(sc1, 0.2f * sc1);
        const float p1 = __builtin_amdgcn_exp2f(sc1) * w1;
        den += p0 + p1;
        num = fmaf(p0, rec0.y, num);
        num = fmaf(p1, rec1.y, num);

        ep0 = en0; ep1 = en1; i += 32;
    }

    // merge 16 subgroups (lane bits 2..5)
    #pragma unroll
    for (int off = 4; off <= 32; off <<= 1) {
        den += __shfl_xor(den, off, 64);
        num += __shfl_xor(num, off, 64);
    }

    float v = num / (den + 1e-16f);
    v += __shfl_xor(v, 1, 64);
    v += __shfl_xor(v, 2, 64);
    if (lane == 0) outp[n] = v + bhead[0];
}

extern "C" void kernel_launch(void* const* d_in, const int* in_sizes, int n_in,
                              void* d_out, int out_size, void* d_ws, size_t ws_size,
                              hipStream_t stream) {
    const float* x      = (const float*)d_in[0];
    const int*   eidx   = (const int*)d_in[1];
    const float* ew     = (const float*)d_in[2];
    const float* tim    = (const float*)d_in[3];
    const float* omega0 = (const float*)d_in[4];
    const float* phase0 = (const float*)d_in[5];
    const float* W0     = (const float*)d_in[6];
    const float* asrc0  = (const float*)d_in[7];
    const float* adst0  = (const float*)d_in[8];
    const float* omega1 = (const float*)d_in[9];
    const float* phase1 = (const float*)d_in[10];
    const float* W1     = (const float*)d_in[11];
    const float* asrc1  = (const float*)d_in[12];
    const float* adst1  = (const float*)d_in[13];
    const float* Whead  = (const float*)d_in[14];
    const float* bhead  = (const float*)d_in[15];
    float* out = (float*)d_out;

    const int* src = eidx;
    const int* dst = eidx + N_EDGES;

    float* ws = (float*)d_ws;
    unsigned short* hfeat16 = (unsigned short*)ws;   // N*64 ushorts (6.4MB)
    float* x1    = (float*)(hfeat16 + (size_t)N_NODES * 64);  // N*64 floats
    float* s_src = x1    + (size_t)N_NODES * 64;     // N*4
    float* s_dst = s_src + (size_t)N_NODES * 4;      // N*4
    int2* epair  = (int2*)(s_dst + (size_t)N_NODES * 4);   // E int2
    int* deg     = (int*)(epair + (size_t)N_EDGES);  // N
    int* rowptr  = deg + N_NODES;                    // N
    int* bstart  = rowptr + N_NODES;                 // NBK+1
    int* cmat    = bstart + NBK + 1;                 // BIN_GRID*NBK (153KB)
    float* l1tab = (float*)(cmat + BIN_GRID * NBK);  // N*8 floats (1.6MB)
    // record arrays alias dead buffers: consumed by place() before their
    // aliases are written (hfeat16 by transform<128>, x1 by aggregate).
    int*  rdst  = (int*)hfeat16;                     // E ints
    int2* rpair = (int2*)x1;                         // E int2

    const int tf_grid  = (N_NODES + 63) / 64;        // 782
    const int agg_grid = (N_NODES + 3) / 4;

    // ---- CSR build (count-matrix bucket sort; shared by both layers) ----
    count_kernel<<<BIN_GRID, 256, 0, stream>>>(dst, cmat);
    cscan_kernel<<<1, 256, 0, stream>>>(cmat, bstart);
    bin_kernel<<<BIN_GRID, 256, 0, stream>>>(dst, src, ew, cmat, bstart, rdst, rpair);
    place_kernel<<<NBK, 256, 0, stream>>>(bstart, rdst, rpair, deg, rowptr, epair);

    // ---- layer 0 ----
    transform_kernel<128, 0><<<tf_grid, 256, 0, stream>>>(
        x, tim, omega0, phase0, W0, asrc0, adst0, Whead,
        hfeat16, s_src, s_dst, l1tab);
    aggregate_kernel<<<agg_grid, 256, 0, stream>>>(
        rowptr, deg, epair, s_src, s_dst, hfeat16, x1);

    // ---- layer 1 (head-collapsed: h@Whead folded into per-node hw) ----
    transform_kernel<64, 1><<<tf_grid, 256, 0, stream>>>(
        x1, tim, omega1, phase1, W1, asrc1, adst1, Whead,
        hfeat16, s_src, s_dst, l1tab);
    head_aggregate_kernel<<<agg_grid, 256, 0, stream>>>(
        rowptr, deg, epair, l1tab, s_dst, bhead, out);
}